// Round 10
// baseline (955.349 us; speedup 1.0000x reference)
//
#include <hip/hip_runtime.h>
#include <cstddef>

#define DEVFN __device__ __forceinline__

typedef __attribute__((ext_vector_type(8))) short short8;          // 8 bf16
typedef __attribute__((ext_vector_type(8))) unsigned short ushort8;
typedef __attribute__((ext_vector_type(4))) float f32x4;           // MFMA acc

DEVFN float sigmoidf_(float x) { return 1.0f / (1.0f + __expf(-x)); }
DEVFN float tanh_fast(float x) {
    float e = __expf(2.0f * x);
    return 1.0f - 2.0f / (e + 1.0f);
}
DEVFN unsigned short f2bf(float f) {            // round-to-nearest-even
    unsigned int u = __float_as_uint(f);
    return (unsigned short)((u + 0x7FFFu + ((u >> 16) & 1u)) >> 16);
}
DEVFN float b2f(unsigned int bits) { return __uint_as_float(bits << 16); }

DEVFN void gload_lds16(const ushort* g, ushort* l) {
    __builtin_amdgcn_global_load_lds(
        (const __attribute__((address_space(1))) unsigned int*)g,
        (__attribute__((address_space(3))) unsigned int*)l, 16, 0, 0);
}

// Padded NHWC geometry: [16 b][66 hs][514 ws][32 c], hs = h+1, ws = w+1.
#define PADN 17371008u

// ---------------------------------------------------------------------------
// Zero the padding ring of the 2 padded NHWC tensors.
// ---------------------------------------------------------------------------
__global__ __launch_bounds__(256)
void ring_zero(ushort* A, ushort* B)
{
    int idx = blockIdx.x * 256 + threadIdx.x;
    if (idx >= 296960) return;
    size_t uoff;
    if (idx < 263168) {                       // rows hs in {0,65}
        int b = idx / 16448, r = idx % 16448;
        int hs = (r < 8224) ? 0 : 65;
        int o = (r < 8224) ? r : r - 8224;
        uoff = (((size_t)(b * 66 + hs) * 514) * 32 + (size_t)o * 2) >> 1;
    } else {                                  // cols ws in {0,513}
        int j = idx - 263168;
        int b = j / 2112, r = j % 2112;
        int hs = r >> 5, e = r & 31;
        int wsp = (e < 16) ? 0 : 513;
        int c2 = e & 15;
        uoff = (((size_t)(b * 66 + hs) * 514 + wsp) * 32 + (size_t)c2 * 2) >> 1;
    }
    ((uint*)A)[uoff] = 0; ((uint*)B)[uoff] = 0;
}

// ---------------------------------------------------------------------------
// Conv-weight prep: [co][ci][3][3] fp32 -> [lay][q][co][ci] bf16 hi/lo.
// ---------------------------------------------------------------------------
__global__ __launch_bounds__(256)
void conv_wprep(const float* __restrict__ c1w, const float* __restrict__ c2w,
                ushort* __restrict__ whi, ushort* __restrict__ wlo)
{
    const int lay = blockIdx.x;               // 0..5
    const int i = lay >> 1;
    const float* src = (lay & 1) ? (c2w + i * 9216) : (c1w + i * 9216);
    for (int e = threadIdx.x; e < 9216; e += 256) {
        int co = e / 288, rem = e % 288, ci = rem / 9, q = rem % 9;
        float v = src[e];
        unsigned short hi = f2bf(v);
        unsigned short lo = f2bf(v - b2f(hi));
        int dst = ((lay * 9 + q) * 32 + co) * 32 + ci;
        whi[dst] = hi; wlo[dst] = lo;
    }
}

// ---------------------------------------------------------------------------
// Conv stem -> padded NHWC bf16. x (16,1,128,1024), stride 2, pad 1.
// ---------------------------------------------------------------------------
__global__ __launch_bounds__(256)
void conv_stem_p(const float* __restrict__ x, const float* __restrict__ w,
                 const float* __restrict__ cb, ushort* __restrict__ Xhi)
{
    const int b = blockIdx.z;
    const int h = blockIdx.y * 4 + (threadIdx.x >> 6);
    const int wc = blockIdx.x * 64 + (threadIdx.x & 63);
    float iv[9];
#pragma unroll
    for (int kh = 0; kh < 3; ++kh)
#pragma unroll
        for (int kw = 0; kw < 3; ++kw) {
            int ih = 2 * h - 1 + kh, iw = 2 * wc - 1 + kw;
            iv[kh * 3 + kw] = (ih >= 0 && ih < 128 && iw >= 0 && iw < 1024)
                ? x[(size_t)b * 131072 + (size_t)ih * 1024 + iw] : 0.0f;
        }
    unsigned short hi[32];
#pragma unroll
    for (int co = 0; co < 32; ++co) {
        const float* wp = w + co * 9;
        float a = cb[co];
#pragma unroll
        for (int q = 0; q < 9; ++q) a = fmaf(iv[q], wp[q], a);
        hi[co] = f2bf(a);
    }
    const size_t o = ((size_t)(b * 66 + h + 1) * 514 + wc + 1) * 32;
#pragma unroll
    for (int v = 0; v < 4; ++v) {
        ushort8 uh;
#pragma unroll
        for (int e = 0; e < 8; ++e) uh[e] = hi[v * 8 + e];
        *(ushort8*)(Xhi + o + v * 8) = uh;
    }
}

// ---------------------------------------------------------------------------
// MFMA implicit-GEMM conv 3x3 (32->32) + BN (+res) + ReLU. (round-8 version)
// ---------------------------------------------------------------------------
template <int RES>
__global__ __launch_bounds__(256)
void conv_mfma(const ushort* __restrict__ Phi,
               const ushort* __restrict__ gwhi, const ushort* __restrict__ gwlo,
               const float* __restrict__ g, const float* __restrict__ bbn,
               const float* __restrict__ mn, const float* __restrict__ vn,
               const float* __restrict__ cbv,
               const ushort* __restrict__ Rhi, ushort* __restrict__ Ohi)
{
    __shared__ __align__(16) ushort Wsh[9216], Wsl[9216];
    const int tid = threadIdx.x, lane = tid & 63, wv = tid >> 6;
    const int b = blockIdx.z, h0 = blockIdx.y * 4, w0 = blockIdx.x * 128;

    for (int i = tid; i < 1152; i += 256) {
        ((uint4*)Wsh)[i] = ((const uint4*)gwhi)[i];
        ((uint4*)Wsl)[i] = ((const uint4*)gwlo)[i];
    }
    __syncthreads();

    const int wr = wv * 32;
    const int fr = lane & 15, fk = (lane >> 4) * 8;
    const int lo0 = (wr + fr) * 32 + fk;
    const int lo1 = (wr + 16 + fr) * 32 + fk;

    float sc[2], sh[2];
#pragma unroll
    for (int n = 0; n < 2; ++n) {
        const int co = n * 16 + fr;
        sc[n] = g[co] * rsqrtf(vn[co] + 1e-5f);
        sh[n] = bbn[co] - mn[co] * sc[n] + cbv[co] * sc[n];
    }

    short8 A[3][2][3];
#define LOADROW(SL, PR)                                                        \
    {                                                                          \
        const size_t rb_ = ((size_t)(b * 66 + (PR)) * 514 + w0) * 32;          \
        _Pragma("unroll")                                                      \
        for (int kw_ = 0; kw_ < 3; ++kw_) {                                    \
            A[SL][0][kw_] = *(const short8*)(Phi + rb_ + kw_ * 32 + lo0);      \
            A[SL][1][kw_] = *(const short8*)(Phi + rb_ + kw_ * 32 + lo1);      \
        }                                                                      \
    }

    LOADROW(0, h0);
    LOADROW(1, h0 + 1);

#pragma unroll
    for (int hh = 0; hh < 4; ++hh) {
        LOADROW((hh + 2) % 3, h0 + hh + 2);
        f32x4 acc[2][2];
#pragma unroll
        for (int m = 0; m < 2; ++m)
#pragma unroll
            for (int n = 0; n < 2; ++n) acc[m][n] = (f32x4){0.f, 0.f, 0.f, 0.f};
#pragma unroll
        for (int kh = 0; kh < 3; ++kh) {
            const int sl = (hh + kh) % 3;
#pragma unroll
            for (int kw = 0; kw < 3; ++kw) {
                const int q = kh * 3 + kw;
                short8 ah0 = A[sl][0][kw];
                short8 ah1 = A[sl][1][kw];
                short8 bh0 = *(const short8*)&Wsh[q * 1024 + fr * 32 + fk];
                short8 bh1 = *(const short8*)&Wsh[q * 1024 + (16 + fr) * 32 + fk];
                short8 bl0 = *(const short8*)&Wsl[q * 1024 + fr * 32 + fk];
                short8 bl1 = *(const short8*)&Wsl[q * 1024 + (16 + fr) * 32 + fk];
                acc[0][0] = __builtin_amdgcn_mfma_f32_16x16x32_bf16(ah0, bh0, acc[0][0], 0, 0, 0);
                acc[0][1] = __builtin_amdgcn_mfma_f32_16x16x32_bf16(ah0, bh1, acc[0][1], 0, 0, 0);
                acc[1][0] = __builtin_amdgcn_mfma_f32_16x16x32_bf16(ah1, bh0, acc[1][0], 0, 0, 0);
                acc[1][1] = __builtin_amdgcn_mfma_f32_16x16x32_bf16(ah1, bh1, acc[1][1], 0, 0, 0);
                acc[0][0] = __builtin_amdgcn_mfma_f32_16x16x32_bf16(ah0, bl0, acc[0][0], 0, 0, 0);
                acc[0][1] = __builtin_amdgcn_mfma_f32_16x16x32_bf16(ah0, bl1, acc[0][1], 0, 0, 0);
                acc[1][0] = __builtin_amdgcn_mfma_f32_16x16x32_bf16(ah1, bl0, acc[1][0], 0, 0, 0);
                acc[1][1] = __builtin_amdgcn_mfma_f32_16x16x32_bf16(ah1, bl1, acc[1][1], 0, 0, 0);
            }
        }
#pragma unroll
        for (int m = 0; m < 2; ++m)
#pragma unroll
            for (int r = 0; r < 4; ++r) {
                const int wl = wr + m * 16 + (lane >> 4) * 4 + r;
                const size_t oidx =
                    ((size_t)(b * 66 + h0 + hh + 1) * 514 + w0 + wl + 1) * 32;
#pragma unroll
                for (int n = 0; n < 2; ++n) {
                    const int co = n * 16 + fr;
                    float val = acc[m][n][r] * sc[n] + sh[n];
                    if (RES) val += b2f(Rhi[oidx + co]);
                    val = fmaxf(val, 0.0f);
                    Ohi[oidx + co] = f2bf(val);
                }
            }
    }
#undef LOADROW
}

// ---------------------------------------------------------------------------
// Gather: padded NHWC -> xrow_bf[(w*16+b)][c*64+h]  (8192 x 2048 bf16)
// ---------------------------------------------------------------------------
__global__ __launch_bounds__(256)
void gather_pad(const ushort* __restrict__ Xhi, ushort* __restrict__ xrow)
{
    __shared__ ushort tile[64 * 16 * 32];        // [h][wl][c], 64 KB
    const int b = blockIdx.y, w0 = blockIdx.x * 16;
    for (int k = threadIdx.x; k < 4096; k += 256) {
        int h = k >> 6, rem = k & 63, wl = rem >> 2, c8 = (rem & 3) * 8;
        const ushort* src = Xhi + ((size_t)(b * 66 + h + 1) * 514 + w0 + 1 + wl) * 32 + c8;
        *(ushort8*)&tile[(h * 16 + wl) * 32 + c8] = *(const ushort8*)src;
    }
    __syncthreads();
    for (int k = threadIdx.x; k < 4096; k += 256) {
        int wl = k >> 8, rem = k & 255, c = rem >> 3, h8 = (rem & 7) * 8;
        ushort8 v;
#pragma unroll
        for (int e = 0; e < 8; ++e) v[e] = tile[((h8 + e) * 16 + wl) * 32 + c];
        *(ushort8*)&xrow[((size_t)(w0 + wl) * 16 + b) * 2048 + c * 64 + h8] = v;
    }
}

// ---------------------------------------------------------------------------
// Weight transpose+convert: W [K][N] fp32 -> Bt [N'][K] bf16.
// perm=1 (SRU): within N=2048, n = gate*512+j -> n' = j*4+gate.
// ---------------------------------------------------------------------------
__global__ __launch_bounds__(256)
void wconv_t(const float* __restrict__ W, ushort* __restrict__ Bt,
             int K, int N, int perm, size_t wstr, size_t btstr)
{
    __shared__ float tile[64][65];
    const float* Wp = W + (size_t)blockIdx.z * wstr;
    ushort* Btp = Bt + (size_t)blockIdx.z * btstr;
    const int k0 = blockIdx.x * 64;
    const int n0 = blockIdx.y * 64;
#pragma unroll
    for (int p = 0; p < 16; ++p) {
        int idx = p * 256 + threadIdx.x;
        int kl = idx >> 6, nl = idx & 63;
        tile[kl][nl] = Wp[(size_t)(k0 + kl) * N + n0 + nl];
    }
    __syncthreads();
#pragma unroll
    for (int p = 0; p < 16; ++p) {
        int idx = p * 256 + threadIdx.x;
        int nl = idx >> 6, kl = idx & 63;
        int n = n0 + nl;
        int row = perm ? ((n & 511) * 4 + (n >> 9)) : n;
        Btp[(size_t)row * K + k0 + kl] = f2bf(tile[kl][nl]);
    }
}

// ---------------------------------------------------------------------------
// LayerNorm over last dim (1024), rows = 8192, fp32 in -> bf16 out.
// ---------------------------------------------------------------------------
__global__ __launch_bounds__(256)
void layernorm1024_bf(const float* __restrict__ x, const float* __restrict__ g,
                      const float* __restrict__ b, ushort* __restrict__ y)
{
    const size_t row = blockIdx.x;
    const float4 v = ((const float4*)(x + row * 1024))[threadIdx.x];
    float s = v.x + v.y + v.z + v.w;
    float s2 = v.x * v.x + v.y * v.y + v.z * v.z + v.w * v.w;
#pragma unroll
    for (int off = 32; off; off >>= 1) {
        s += __shfl_down(s, off);
        s2 += __shfl_down(s2, off);
    }
    __shared__ float red[2][4];
    int wid = threadIdx.x >> 6, lane = threadIdx.x & 63;
    if (lane == 0) { red[0][wid] = s; red[1][wid] = s2; }
    __syncthreads();
    s = red[0][0] + red[0][1] + red[0][2] + red[0][3];
    s2 = red[1][0] + red[1][1] + red[1][2] + red[1][3];
    float mu = s * (1.0f / 1024.0f);
    float var = s2 * (1.0f / 1024.0f) - mu * mu;
    float rstd = rsqrtf(var + 1e-5f);
    float4 gv = ((const float4*)g)[threadIdx.x];
    float4 bv = ((const float4*)b)[threadIdx.x];
    ushort4 o;
    o.x = f2bf((v.x - mu) * rstd * gv.x + bv.x);
    o.y = f2bf((v.y - mu) * rstd * gv.y + bv.y);
    o.z = f2bf((v.z - mu) * rstd * gv.z + bv.z);
    o.w = f2bf((v.w - mu) * rstd * gv.w + bv.w);
    ((ushort4*)(y + row * 1024))[threadIdx.x] = o;
}

// ---------------------------------------------------------------------------
// 256x256 8-phase bf16 GEMM (m201 template): C[M,N](bf16) = A[M,K] @ Bt[N,K]^T
// ---------------------------------------------------------------------------
__global__ __launch_bounds__(512, 2)
void gemm256_bf16(const ushort* __restrict__ A, const ushort* __restrict__ Bt,
                  ushort* __restrict__ C, int M, int N, int K)
{
    __shared__ __align__(16) ushort LDS[65536];   // A:[2][16384], B:+32768
    const int tid = threadIdx.x;
    const int lane = tid & 63, w = tid >> 6;
    const int wm = w >> 2, wn = w & 3;            // 2 x 4 wave grid
    const int m0 = blockIdx.y * 256, n0 = blockIdx.x * 256;
    const int fr = lane & 15, fk = (lane >> 4) * 8;
    const int NT = K >> 6;

    const int sprow = tid >> 3;                   // row within 64-row quarter
    const int scb0 = (tid & 7) * 16;              // byte col within 128B row
    const int wq = w * 512;                       // wave base (elements) in quarter

    f32x4 acc[8][4];
#pragma unroll
    for (int i = 0; i < 8; ++i)
#pragma unroll
        for (int j = 0; j < 4; ++j) acc[i][j] = (f32x4){0.f, 0.f, 0.f, 0.f};

    auto stage = [&](int dbuf, int isB, int qi, int kt) {
        const int prow = qi * 64 + sprow;
        const int sc = scb0 ^ (((prow >> 2) & 1) << 5);   // inverse swizzle
        const ushort* g = (isB ? (Bt + (size_t)(n0 + prow) * K)
                               : (A + (size_t)(m0 + prow) * K))
                          + (kt << 6) + (sc >> 1);
        gload_lds16(g, LDS + (isB ? 32768 : 0) + dbuf * 16384 + qi * 4096 + wq);
    };
    auto rdA = [&](int dbuf, int mi8, int ks) -> short8 {
        const int row = wm * 128 + mi8 * 16 + fr;
        int e = (row * 64 + ks * 32 + fk) ^ (((row >> 2) & 1) << 4);
        return *(const short8*)&LDS[dbuf * 16384 + e];
    };
    auto rdB = [&](int dbuf, int ni, int ks) -> short8 {
        const int row = wn * 64 + ni * 16 + fr;
        int e = (row * 64 + ks * 32 + fk) ^ (((row >> 2) & 1) << 4);
        return *(const short8*)&LDS[32768 + dbuf * 16384 + e];
    };

#pragma unroll
    for (int qi = 0; qi < 4; ++qi) stage(0, 0, qi, 0);
#pragma unroll
    for (int qi = 0; qi < 4; ++qi) stage(0, 1, qi, 0);

    for (int kt = 0; kt < NT; ++kt) {
        const int cur = kt & 1, nxt = cur ^ 1;
        const bool more = (kt + 1 < NT);
        short8 bfr[4], afr[4];

        // ---- phase 0
        if (more) {
            stage(nxt, 0, 0, kt + 1); stage(nxt, 0, 1, kt + 1);
            asm volatile("s_waitcnt vmcnt(2)" ::: "memory");
        } else {
            asm volatile("s_waitcnt vmcnt(0)" ::: "memory");
        }
        __builtin_amdgcn_s_barrier();
#pragma unroll
        for (int ni = 0; ni < 4; ++ni) bfr[ni] = rdB(cur, ni, 0);
#pragma unroll
        for (int mi = 0; mi < 4; ++mi) afr[mi] = rdA(cur, mi, 0);
        __builtin_amdgcn_s_setprio(1);
#pragma unroll
        for (int mi = 0; mi < 4; ++mi)
#pragma unroll
            for (int ni = 0; ni < 4; ++ni)
                acc[mi][ni] = __builtin_amdgcn_mfma_f32_16x16x32_bf16(
                    afr[mi], bfr[ni], acc[mi][ni], 0, 0, 0);
        __builtin_amdgcn_s_setprio(0);

        // ---- phase 1
        if (more) { stage(nxt, 0, 2, kt + 1); stage(nxt, 0, 3, kt + 1); }
#pragma unroll
        for (int mi = 0; mi < 4; ++mi) afr[mi] = rdA(cur, 4 + mi, 0);
        __builtin_amdgcn_s_setprio(1);
#pragma unroll
        for (int mi = 0; mi < 4; ++mi)
#pragma unroll
            for (int ni = 0; ni < 4; ++ni)
                acc[4 + mi][ni] = __builtin_amdgcn_mfma_f32_16x16x32_bf16(
                    afr[mi], bfr[ni], acc[4 + mi][ni], 0, 0, 0);
        __builtin_amdgcn_s_setprio(0);

        // ---- phase 2
        if (more) { stage(nxt, 1, 0, kt + 1); stage(nxt, 1, 1, kt + 1); }
#pragma unroll
        for (int ni = 0; ni < 4; ++ni) bfr[ni] = rdB(cur, ni, 1);
#pragma unroll
        for (int mi = 0; mi < 4; ++mi) afr[mi] = rdA(cur, mi, 1);
        __builtin_amdgcn_s_setprio(1);
#pragma unroll
        for (int mi = 0; mi < 4; ++mi)
#pragma unroll
            for (int ni = 0; ni < 4; ++ni)
                acc[mi][ni] = __builtin_amdgcn_mfma_f32_16x16x32_bf16(
                    afr[mi], bfr[ni], acc[mi][ni], 0, 0, 0);
        __builtin_amdgcn_s_setprio(0);

        // ---- phase 3
        if (more) { stage(nxt, 1, 2, kt + 1); stage(nxt, 1, 3, kt + 1); }
#pragma unroll
        for (int mi = 0; mi < 4; ++mi) afr[mi] = rdA(cur, 4 + mi, 1);
        __builtin_amdgcn_s_setprio(1);
#pragma unroll
        for (int mi = 0; mi < 4; ++mi)
#pragma unroll
            for (int ni = 0; ni < 4; ++ni)
                acc[4 + mi][ni] = __builtin_amdgcn_mfma_f32_16x16x32_bf16(
                    afr[mi], bfr[ni], acc[4 + mi][ni], 0, 0, 0);
        __builtin_amdgcn_s_setprio(0);

        __builtin_amdgcn_s_barrier();     // all waves done reading buf cur
    }

    // epilogue: bf16 C-tile via LDS
#pragma unroll
    for (int mi8 = 0; mi8 < 8; ++mi8)
#pragma unroll
        for (int r = 0; r < 4; ++r) {
            const int row = wm * 128 + mi8 * 16 + (lane >> 4) * 4 + r;
#pragma unroll
            for (int ni = 0; ni < 4; ++ni)
                LDS[row * 256 + wn * 64 + ni * 16 + fr] = f2bf(acc[mi8][ni][r]);
        }
    __builtin_amdgcn_s_barrier();
    const int frow = tid >> 5, fcb = (tid & 31) * 8;
#pragma unroll
    for (int it = 0; it < 16; ++it) {
        const int row = it * 16 + frow;
        ushort8 vv = *(const ushort8*)&LDS[row * 256 + fcb];
        *(ushort8*)&C[(size_t)(m0 + row) * N + n0 + fcb] = vv;
    }
}

// ---------------------------------------------------------------------------
// bf16 MFMA GEMM (128² 2-phase) — used for proj and classifier (fp32 out).
// ---------------------------------------------------------------------------
template <int RELU>
__global__ __launch_bounds__(256)
void gemm_bf16(const ushort* __restrict__ A, const ushort* __restrict__ Bt,
               float* __restrict__ C, int M, int N, int K)
{
    __shared__ __align__(16) ushort Sh[4][4096];   // [0..1]=A dbuf, [2..3]=B dbuf
    const int tid = threadIdx.x;
    const int lane = tid & 63, w = tid >> 6;
    const int m0 = blockIdx.y * 128, n0 = blockIdx.x * 128;
    const int srow = lane >> 2;
    const int skel = (lane & 3) * 8;
    const int wr = (w >> 1) * 64, wcol = (w & 1) * 64;
    const int fr = lane & 15, fk = (lane >> 4) * 8;

    f32x4 acc[4][4];
#pragma unroll
    for (int m = 0; m < 4; ++m)
#pragma unroll
        for (int n = 0; n < 4; ++n) acc[m][n] = (f32x4){0.f, 0.f, 0.f, 0.f};

#pragma unroll
    for (int q = 0; q < 2; ++q) {
        const int ch = w * 2 + q;
        gload_lds16(A + (size_t)(m0 + ch * 16 + srow) * K + skel, &Sh[0][ch * 512]);
        gload_lds16(Bt + (size_t)(n0 + ch * 16 + srow) * K + skel, &Sh[2][ch * 512]);
    }
    __syncthreads();

    int cur = 0;
    for (int k0 = 0; k0 < K; k0 += 32) {
        if (k0 + 32 < K) {
#pragma unroll
            for (int q = 0; q < 2; ++q) {
                const int ch = w * 2 + q;
                gload_lds16(A + (size_t)(m0 + ch * 16 + srow) * K + k0 + 32 + skel,
                            &Sh[cur ^ 1][ch * 512]);
                gload_lds16(Bt + (size_t)(n0 + ch * 16 + srow) * K + k0 + 32 + skel,
                            &Sh[2 + (cur ^ 1)][ch * 512]);
            }
        }
        short8 a[4], b[4];
#pragma unroll
        for (int m = 0; m < 4; ++m)
            a[m] = *(const short8*)&Sh[cur][(wr + m * 16 + fr) * 32 + fk];
#pragma unroll
        for (int n = 0; n < 4; ++n)
            b[n] = *(const short8*)&Sh[2 + cur][(wcol + n * 16 + fr) * 32 + fk];
#pragma unroll
        for (int m = 0; m < 4; ++m)
#pragma unroll
            for (int n = 0; n < 4; ++n)
                acc[m][n] = __builtin_amdgcn_mfma_f32_16x16x32_bf16(
                    a[m], b[n], acc[m][n], 0, 0, 0);
        __syncthreads();
        cur ^= 1;
    }
#pragma unroll
    for (int m = 0; m < 4; ++m) {
#pragma unroll
        for (int r = 0; r < 4; ++r) {
            const int row = m0 + wr + m * 16 + (lane >> 4) * 4 + r;
            const size_t rb = (size_t)row * N;
#pragma unroll
            for (int n = 0; n < 4; ++n) {
                float val = acc[m][n][r];
                if (RELU) val = fmaxf(val, 0.0f);
                C[rb + n0 + wcol + n * 16 + fr] = val;
            }
        }
    }
}

// ---------------------------------------------------------------------------
// Fused bidirectional SRU scan (U bf16, gate-interleaved cols).
// v3: rolling-window prefetch — single buf[16], each step consumes slot q
// then refills it from 16 steps ahead (static indices after unroll -> all
// registers, ~600cy lookahead per load). 256 blocks x 64 thr = all CUs.
// ---------------------------------------------------------------------------
__global__ __launch_bounds__(64)
void sru_scan2(const ushort* __restrict__ U, const float* __restrict__ v,
               const float* __restrict__ bb, float* __restrict__ out)
{
    const int gidx = blockIdx.x * 64 + threadIdx.x;    // 0..16383
    const int dir = gidx >> 13;
    const int idx = gidx & 8191;
    const int j = idx & 511, b = idx >> 9;
    const float vf = v[dir * 1024 + j],   vr = v[dir * 1024 + 512 + j];
    const float bf_ = bb[dir * 1024 + j], br_ = bb[dir * 1024 + 512 + j];
    const size_t cb = (size_t)dir * 2048 + j * 4;
    const int co = dir * 512 + j;
#define TT(q_) (dir ? (511 - (q_)) : (q_))
    float c = 0.0f;
    uint2 buf[16];
#pragma unroll
    for (int q = 0; q < 16; ++q)
        buf[q] = *(const uint2*)&U[((size_t)(TT(q) * 16 + b) << 12) + cb];
    for (int base = 0; base < 512; base += 16) {
#pragma unroll
        for (int q = 0; q < 16; ++q) {
            const int s = base + q;
            const int t = TT(s);
            float xt = b2f(buf[q].x & 0xffffu);
            float fp = b2f(buf[q].x >> 16);
            float rp = b2f(buf[q].y & 0xffffu);
            float xp = b2f(buf[q].y >> 16);
            const int sn = s + 16;
            if (sn < 512)                          // refill freed slot early
                buf[q] = *(const uint2*)&U[((size_t)(TT(sn) * 16 + b) << 12) + cb];
            float f = sigmoidf_(fp + vf * c + bf_);
            float r = sigmoidf_(rp + vr * c + br_);
            c = fmaf(f, c - xt, xt);
            float h = fmaf(r, tanh_fast(c) - xp, xp);
            out[((size_t)(t * 16 + b) << 10) + co] = h;
        }
    }
#undef TT
}

// ---------------------------------------------------------------------------
// Final small GEMM (8192,512)@(512,29) with (t,b)->(b,t) output scatter.
// ---------------------------------------------------------------------------
__global__ __launch_bounds__(256)
void cls_out(const float* __restrict__ h1, const float* __restrict__ W2,
             float* __restrict__ out)
{
    const int gidx = blockIdx.x * 256 + threadIdx.x;
    const int n = gidx & 31, m = gidx >> 5;
    if (n >= 29) return;
    const float4* hr = (const float4*)(h1 + (size_t)m * 512);
    float acc = 0.0f;
    for (int k4 = 0; k4 < 128; ++k4) {
        float4 hv = hr[k4];
        const float* wp = W2 + (size_t)(k4 * 4) * 29 + n;
        acc = fmaf(hv.x, wp[0],  acc);
        acc = fmaf(hv.y, wp[29], acc);
        acc = fmaf(hv.z, wp[58], acc);
        acc = fmaf(hv.w, wp[87], acc);
    }
    const int t = m >> 4, b = m & 15;
    out[((size_t)b * 512 + t) * 29 + n] = acc;
}

// ---------------------------------------------------------------------------
// Host orchestration. Workspace layout identical to rounds 7-9.
// ---------------------------------------------------------------------------
extern "C" void kernel_launch(void* const* d_in, const int* in_sizes, int n_in,
                              void* d_out, int out_size, void* d_ws, size_t ws_size,
                              hipStream_t stream)
{
    (void)in_sizes; (void)n_in; (void)out_size; (void)ws_size;
    const float* x      = (const float*)d_in[0];
    const float* cnn_w  = (const float*)d_in[1];
    const float* cnn_b  = (const float*)d_in[2];
    const float* c1w    = (const float*)d_in[3];
    const float* c1b    = (const float*)d_in[4];
    const float* bn1g   = (const float*)d_in[5];
    const float* bn1b   = (const float*)d_in[6];
    const float* bn1m   = (const float*)d_in[7];
    const float* bn1v   = (const float*)d_in[8];
    const float* c2w    = (const float*)d_in[9];
    const float* c2b    = (const float*)d_in[10];
    const float* bn2g   = (const float*)d_in[11];
    const float* bn2b   = (const float*)d_in[12];
    const float* bn2m   = (const float*)d_in[13];
    const float* bn2v   = (const float*)d_in[14];
    const float* projW  = (const float*)d_in[15];
    const float* sruW   = (const float*)d_in[16];
    const float* sruV   = (const float*)d_in[17];
    const float* sruB   = (const float*)d_in[18];
    const float* sruLNg = (const float*)d_in[19];
    const float* sruLNb = (const float*)d_in[20];
    const float* clsLNg = (const float*)d_in[21];
    const float* clsLNb = (const float*)d_in[22];
    const float* W1     = (const float*)d_in[23];
    const float* W2     = (const float*)d_in[24];
    float* out = (float*)d_out;
    float* ws  = (float*)d_ws;

    ushort* Xhi = (ushort*)ws;
    ushort* Thi = Xhi + PADN;
    ushort* convw_hi = (ushort*)(ws + 34742016);
    ushort* convw_lo = convw_hi + 55296;
    ushort* xrow_bf  = (ushort*)(ws + 34865152);   // [8192][2048]
    ushort* xn_bf    = (ushort*)(ws + 43253760);   // [8192][1024]
    ushort* Ubuf     = (ushort*)ws;                // [8192][4096]
    float*  xch      = ws + 16777216;              // [8192][1024] fp32
    ushort* proj_bt  = (ushort*)(ws + 25165824);   // [1024][2048]
    ushort* sru_bt   = (ushort*)(ws + 26214400);   // 8 x [2048][1024]
    ushort* w1t      = (ushort*)(ws + 34603008);   // [512][1024]
    float*  h1       = ws;                         // [8192][512] fp32

    dim3 blk(256);

    // --- conv phase ---
    ring_zero<<<1160, blk, 0, stream>>>(Xhi, Thi);
    conv_wprep<<<6, blk, 0, stream>>>(c1w, c2w, convw_hi, convw_lo);
    conv_stem_p<<<dim3(8, 16, 16), blk, 0, stream>>>(x, cnn_w, cnn_b, Xhi);
    for (int i = 0; i < 3; ++i) {
        const int l1 = 2 * i, l2 = 2 * i + 1;
        conv_mfma<0><<<dim3(4, 16, 16), blk, 0, stream>>>(
            Xhi, convw_hi + l1 * 9216, convw_lo + l1 * 9216,
            bn1g + i * 32, bn1b + i * 32, bn1m + i * 32, bn1v + i * 32,
            c1b + i * 32, nullptr, Thi);
        conv_mfma<1><<<dim3(4, 16, 16), blk, 0, stream>>>(
            Thi, convw_hi + l2 * 9216, convw_lo + l2 * 9216,
            bn2g + i * 32, bn2b + i * 32, bn2m + i * 32, bn2v + i * 32,
            c2b + i * 32, Xhi, Xhi);
    }

    // --- GEMM weight conversion (SRU batched via z) ---
    wconv_t<<<dim3(32, 16, 1), blk, 0, stream>>>(projW, proj_bt, 2048, 1024, 0, 0, 0);
    wconv_t<<<dim3(16, 32, 8), blk, 0, stream>>>(sruW, sru_bt, 1024, 2048, 1,
                                                 2097152, 2097152);
    wconv_t<<<dim3(16, 8, 1), blk, 0, stream>>>(W1, w1t, 1024, 512, 0, 0, 0);

    // --- gather to bf16 rows ---
    gather_pad<<<dim3(32, 16), blk, 0, stream>>>(Xhi, xrow_bf);

    // --- proj GEMM: (8192,2048)@(2048,1024) -> xch fp32 ---
    gemm_bf16<0><<<dim3(8, 64), blk, 0, stream>>>(
        xrow_bf, proj_bt, xch, 8192, 1024, 2048);

    // --- SRU layers ---
    for (int l = 0; l < 4; ++l) {
        layernorm1024_bf<<<8192, blk, 0, stream>>>(
            xch, sruLNg + l * 1024, sruLNb + l * 1024, xn_bf);
        gemm256_bf16<<<dim3(16, 32), dim3(512), 0, stream>>>(
            xn_bf, sru_bt + (size_t)l * 4194304, Ubuf, 8192, 4096, 1024);
        sru_scan2<<<256, dim3(64), 0, stream>>>(
            Ubuf, sruV + l * 2048, sruB + l * 2048, xch);
    }

    // --- classifier ---
    layernorm1024_bf<<<8192, blk, 0, stream>>>(xch, clsLNg, clsLNb, xn_bf);
    gemm_bf16<1><<<dim3(4, 64), blk, 0, stream>>>(
        xn_bf, w1t, h1, 8192, 512, 1024);
    cls_out<<<1024, blk, 0, stream>>>(h1, W2, out);
}

// Round 11
// 936.126 us; speedup vs baseline: 1.0205x; 1.0205x over previous
//
#include <hip/hip_runtime.h>
#include <cstddef>

#define DEVFN __device__ __forceinline__

typedef __attribute__((ext_vector_type(8))) short short8;          // 8 bf16
typedef __attribute__((ext_vector_type(8))) unsigned short ushort8;
typedef __attribute__((ext_vector_type(4))) float f32x4;           // MFMA acc
typedef __attribute__((ext_vector_type(2))) unsigned int u32x2;    // dwordx2

DEVFN float sigmoidf_(float x) { return 1.0f / (1.0f + __expf(-x)); }
DEVFN float tanh_fast(float x) {
    float e = __expf(2.0f * x);
    return 1.0f - 2.0f / (e + 1.0f);
}
DEVFN unsigned short f2bf(float f) {            // round-to-nearest-even
    unsigned int u = __float_as_uint(f);
    return (unsigned short)((u + 0x7FFFu + ((u >> 16) & 1u)) >> 16);
}
DEVFN float b2f(unsigned int bits) { return __uint_as_float(bits << 16); }

DEVFN void gload_lds16(const ushort* g, ushort* l) {
    __builtin_amdgcn_global_load_lds(
        (const __attribute__((address_space(1))) unsigned int*)g,
        (__attribute__((address_space(3))) unsigned int*)l, 16, 0, 0);
}

// Padded NHWC geometry: [16 b][66 hs][514 ws][32 c], hs = h+1, ws = w+1.
#define PADN 17371008u

// ---------------------------------------------------------------------------
// Zero the padding ring of the 2 padded NHWC tensors.
// ---------------------------------------------------------------------------
__global__ __launch_bounds__(256)
void ring_zero(ushort* A, ushort* B)
{
    int idx = blockIdx.x * 256 + threadIdx.x;
    if (idx >= 296960) return;
    size_t uoff;
    if (idx < 263168) {                       // rows hs in {0,65}
        int b = idx / 16448, r = idx % 16448;
        int hs = (r < 8224) ? 0 : 65;
        int o = (r < 8224) ? r : r - 8224;
        uoff = (((size_t)(b * 66 + hs) * 514) * 32 + (size_t)o * 2) >> 1;
    } else {                                  // cols ws in {0,513}
        int j = idx - 263168;
        int b = j / 2112, r = j % 2112;
        int hs = r >> 5, e = r & 31;
        int wsp = (e < 16) ? 0 : 513;
        int c2 = e & 15;
        uoff = (((size_t)(b * 66 + hs) * 514 + wsp) * 32 + (size_t)c2 * 2) >> 1;
    }
    ((uint*)A)[uoff] = 0; ((uint*)B)[uoff] = 0;
}

// ---------------------------------------------------------------------------
// Conv-weight prep: [co][ci][3][3] fp32 -> [lay][q][co][ci] bf16 hi/lo.
// ---------------------------------------------------------------------------
__global__ __launch_bounds__(256)
void conv_wprep(const float* __restrict__ c1w, const float* __restrict__ c2w,
                ushort* __restrict__ whi, ushort* __restrict__ wlo)
{
    const int lay = blockIdx.x;               // 0..5
    const int i = lay >> 1;
    const float* src = (lay & 1) ? (c2w + i * 9216) : (c1w + i * 9216);
    for (int e = threadIdx.x; e < 9216; e += 256) {
        int co = e / 288, rem = e % 288, ci = rem / 9, q = rem % 9;
        float v = src[e];
        unsigned short hi = f2bf(v);
        unsigned short lo = f2bf(v - b2f(hi));
        int dst = ((lay * 9 + q) * 32 + co) * 32 + ci;
        whi[dst] = hi; wlo[dst] = lo;
    }
}

// ---------------------------------------------------------------------------
// Conv stem -> padded NHWC bf16. x (16,1,128,1024), stride 2, pad 1.
// ---------------------------------------------------------------------------
__global__ __launch_bounds__(256)
void conv_stem_p(const float* __restrict__ x, const float* __restrict__ w,
                 const float* __restrict__ cb, ushort* __restrict__ Xhi)
{
    const int b = blockIdx.z;
    const int h = blockIdx.y * 4 + (threadIdx.x >> 6);
    const int wc = blockIdx.x * 64 + (threadIdx.x & 63);
    float iv[9];
#pragma unroll
    for (int kh = 0; kh < 3; ++kh)
#pragma unroll
        for (int kw = 0; kw < 3; ++kw) {
            int ih = 2 * h - 1 + kh, iw = 2 * wc - 1 + kw;
            iv[kh * 3 + kw] = (ih >= 0 && ih < 128 && iw >= 0 && iw < 1024)
                ? x[(size_t)b * 131072 + (size_t)ih * 1024 + iw] : 0.0f;
        }
    unsigned short hi[32];
#pragma unroll
    for (int co = 0; co < 32; ++co) {
        const float* wp = w + co * 9;
        float a = cb[co];
#pragma unroll
        for (int q = 0; q < 9; ++q) a = fmaf(iv[q], wp[q], a);
        hi[co] = f2bf(a);
    }
    const size_t o = ((size_t)(b * 66 + h + 1) * 514 + wc + 1) * 32;
#pragma unroll
    for (int v = 0; v < 4; ++v) {
        ushort8 uh;
#pragma unroll
        for (int e = 0; e < 8; ++e) uh[e] = hi[v * 8 + e];
        *(ushort8*)(Xhi + o + v * 8) = uh;
    }
}

// ---------------------------------------------------------------------------
// MFMA implicit-GEMM conv 3x3 (32->32) + BN (+res) + ReLU. (round-8 version)
// ---------------------------------------------------------------------------
template <int RES>
__global__ __launch_bounds__(256)
void conv_mfma(const ushort* __restrict__ Phi,
               const ushort* __restrict__ gwhi, const ushort* __restrict__ gwlo,
               const float* __restrict__ g, const float* __restrict__ bbn,
               const float* __restrict__ mn, const float* __restrict__ vn,
               const float* __restrict__ cbv,
               const ushort* __restrict__ Rhi, ushort* __restrict__ Ohi)
{
    __shared__ __align__(16) ushort Wsh[9216], Wsl[9216];
    const int tid = threadIdx.x, lane = tid & 63, wv = tid >> 6;
    const int b = blockIdx.z, h0 = blockIdx.y * 4, w0 = blockIdx.x * 128;

    for (int i = tid; i < 1152; i += 256) {
        ((uint4*)Wsh)[i] = ((const uint4*)gwhi)[i];
        ((uint4*)Wsl)[i] = ((const uint4*)gwlo)[i];
    }
    __syncthreads();

    const int wr = wv * 32;
    const int fr = lane & 15, fk = (lane >> 4) * 8;
    const int lo0 = (wr + fr) * 32 + fk;
    const int lo1 = (wr + 16 + fr) * 32 + fk;

    float sc[2], sh[2];
#pragma unroll
    for (int n = 0; n < 2; ++n) {
        const int co = n * 16 + fr;
        sc[n] = g[co] * rsqrtf(vn[co] + 1e-5f);
        sh[n] = bbn[co] - mn[co] * sc[n] + cbv[co] * sc[n];
    }

    short8 A[3][2][3];
#define LOADROW(SL, PR)                                                        \
    {                                                                          \
        const size_t rb_ = ((size_t)(b * 66 + (PR)) * 514 + w0) * 32;          \
        _Pragma("unroll")                                                      \
        for (int kw_ = 0; kw_ < 3; ++kw_) {                                    \
            A[SL][0][kw_] = *(const short8*)(Phi + rb_ + kw_ * 32 + lo0);      \
            A[SL][1][kw_] = *(const short8*)(Phi + rb_ + kw_ * 32 + lo1);      \
        }                                                                      \
    }

    LOADROW(0, h0);
    LOADROW(1, h0 + 1);

#pragma unroll
    for (int hh = 0; hh < 4; ++hh) {
        LOADROW((hh + 2) % 3, h0 + hh + 2);
        f32x4 acc[2][2];
#pragma unroll
        for (int m = 0; m < 2; ++m)
#pragma unroll
            for (int n = 0; n < 2; ++n) acc[m][n] = (f32x4){0.f, 0.f, 0.f, 0.f};
#pragma unroll
        for (int kh = 0; kh < 3; ++kh) {
            const int sl = (hh + kh) % 3;
#pragma unroll
            for (int kw = 0; kw < 3; ++kw) {
                const int q = kh * 3 + kw;
                short8 ah0 = A[sl][0][kw];
                short8 ah1 = A[sl][1][kw];
                short8 bh0 = *(const short8*)&Wsh[q * 1024 + fr * 32 + fk];
                short8 bh1 = *(const short8*)&Wsh[q * 1024 + (16 + fr) * 32 + fk];
                short8 bl0 = *(const short8*)&Wsl[q * 1024 + fr * 32 + fk];
                short8 bl1 = *(const short8*)&Wsl[q * 1024 + (16 + fr) * 32 + fk];
                acc[0][0] = __builtin_amdgcn_mfma_f32_16x16x32_bf16(ah0, bh0, acc[0][0], 0, 0, 0);
                acc[0][1] = __builtin_amdgcn_mfma_f32_16x16x32_bf16(ah0, bh1, acc[0][1], 0, 0, 0);
                acc[1][0] = __builtin_amdgcn_mfma_f32_16x16x32_bf16(ah1, bh0, acc[1][0], 0, 0, 0);
                acc[1][1] = __builtin_amdgcn_mfma_f32_16x16x32_bf16(ah1, bh1, acc[1][1], 0, 0, 0);
                acc[0][0] = __builtin_amdgcn_mfma_f32_16x16x32_bf16(ah0, bl0, acc[0][0], 0, 0, 0);
                acc[0][1] = __builtin_amdgcn_mfma_f32_16x16x32_bf16(ah0, bl1, acc[0][1], 0, 0, 0);
                acc[1][0] = __builtin_amdgcn_mfma_f32_16x16x32_bf16(ah1, bl0, acc[1][0], 0, 0, 0);
                acc[1][1] = __builtin_amdgcn_mfma_f32_16x16x32_bf16(ah1, bl1, acc[1][1], 0, 0, 0);
            }
        }
#pragma unroll
        for (int m = 0; m < 2; ++m)
#pragma unroll
            for (int r = 0; r < 4; ++r) {
                const int wl = wr + m * 16 + (lane >> 4) * 4 + r;
                const size_t oidx =
                    ((size_t)(b * 66 + h0 + hh + 1) * 514 + w0 + wl + 1) * 32;
#pragma unroll
                for (int n = 0; n < 2; ++n) {
                    const int co = n * 16 + fr;
                    float val = acc[m][n][r] * sc[n] + sh[n];
                    if (RES) val += b2f(Rhi[oidx + co]);
                    val = fmaxf(val, 0.0f);
                    Ohi[oidx + co] = f2bf(val);
                }
            }
    }
#undef LOADROW
}

// ---------------------------------------------------------------------------
// Gather: padded NHWC -> xrow_bf[(w*16+b)][c*64+h]  (8192 x 2048 bf16)
// ---------------------------------------------------------------------------
__global__ __launch_bounds__(256)
void gather_pad(const ushort* __restrict__ Xhi, ushort* __restrict__ xrow)
{
    __shared__ ushort tile[64 * 16 * 32];        // [h][wl][c], 64 KB
    const int b = blockIdx.y, w0 = blockIdx.x * 16;
    for (int k = threadIdx.x; k < 4096; k += 256) {
        int h = k >> 6, rem = k & 63, wl = rem >> 2, c8 = (rem & 3) * 8;
        const ushort* src = Xhi + ((size_t)(b * 66 + h + 1) * 514 + w0 + 1 + wl) * 32 + c8;
        *(ushort8*)&tile[(h * 16 + wl) * 32 + c8] = *(const ushort8*)src;
    }
    __syncthreads();
    for (int k = threadIdx.x; k < 4096; k += 256) {
        int wl = k >> 8, rem = k & 255, c = rem >> 3, h8 = (rem & 7) * 8;
        ushort8 v;
#pragma unroll
        for (int e = 0; e < 8; ++e) v[e] = tile[((h8 + e) * 16 + wl) * 32 + c];
        *(ushort8*)&xrow[((size_t)(w0 + wl) * 16 + b) * 2048 + c * 64 + h8] = v;
    }
}

// ---------------------------------------------------------------------------
// Weight transpose+convert: W [K][N] fp32 -> Bt [N'][K] bf16.
// perm=1 (SRU): within N=2048, n = gate*512+j -> n' = j*4+gate.
// ---------------------------------------------------------------------------
__global__ __launch_bounds__(256)
void wconv_t(const float* __restrict__ W, ushort* __restrict__ Bt,
             int K, int N, int perm, size_t wstr, size_t btstr)
{
    __shared__ float tile[64][65];
    const float* Wp = W + (size_t)blockIdx.z * wstr;
    ushort* Btp = Bt + (size_t)blockIdx.z * btstr;
    const int k0 = blockIdx.x * 64;
    const int n0 = blockIdx.y * 64;
#pragma unroll
    for (int p = 0; p < 16; ++p) {
        int idx = p * 256 + threadIdx.x;
        int kl = idx >> 6, nl = idx & 63;
        tile[kl][nl] = Wp[(size_t)(k0 + kl) * N + n0 + nl];
    }
    __syncthreads();
#pragma unroll
    for (int p = 0; p < 16; ++p) {
        int idx = p * 256 + threadIdx.x;
        int nl = idx >> 6, kl = idx & 63;
        int n = n0 + nl;
        int row = perm ? ((n & 511) * 4 + (n >> 9)) : n;
        Btp[(size_t)row * K + k0 + kl] = f2bf(tile[kl][nl]);
    }
}

// ---------------------------------------------------------------------------
// LayerNorm over last dim (1024), rows = 8192, fp32 in -> bf16 out.
// ---------------------------------------------------------------------------
__global__ __launch_bounds__(256)
void layernorm1024_bf(const float* __restrict__ x, const float* __restrict__ g,
                      const float* __restrict__ b, ushort* __restrict__ y)
{
    const size_t row = blockIdx.x;
    const float4 v = ((const float4*)(x + row * 1024))[threadIdx.x];
    float s = v.x + v.y + v.z + v.w;
    float s2 = v.x * v.x + v.y * v.y + v.z * v.z + v.w * v.w;
#pragma unroll
    for (int off = 32; off; off >>= 1) {
        s += __shfl_down(s, off);
        s2 += __shfl_down(s2, off);
    }
    __shared__ float red[2][4];
    int wid = threadIdx.x >> 6, lane = threadIdx.x & 63;
    if (lane == 0) { red[0][wid] = s; red[1][wid] = s2; }
    __syncthreads();
    s = red[0][0] + red[0][1] + red[0][2] + red[0][3];
    s2 = red[1][0] + red[1][1] + red[1][2] + red[1][3];
    float mu = s * (1.0f / 1024.0f);
    float var = s2 * (1.0f / 1024.0f) - mu * mu;
    float rstd = rsqrtf(var + 1e-5f);
    float4 gv = ((const float4*)g)[threadIdx.x];
    float4 bv = ((const float4*)b)[threadIdx.x];
    ushort4 o;
    o.x = f2bf((v.x - mu) * rstd * gv.x + bv.x);
    o.y = f2bf((v.y - mu) * rstd * gv.y + bv.y);
    o.z = f2bf((v.z - mu) * rstd * gv.z + bv.z);
    o.w = f2bf((v.w - mu) * rstd * gv.w + bv.w);
    ((ushort4*)(y + row * 1024))[threadIdx.x] = o;
}

// ---------------------------------------------------------------------------
// 256x256 8-phase bf16 GEMM (m201 template): C[M,N](bf16) = A[M,K] @ Bt[N,K]^T
// ---------------------------------------------------------------------------
__global__ __launch_bounds__(512, 2)
void gemm256_bf16(const ushort* __restrict__ A, const ushort* __restrict__ Bt,
                  ushort* __restrict__ C, int M, int N, int K)
{
    __shared__ __align__(16) ushort LDS[65536];   // A:[2][16384], B:+32768
    const int tid = threadIdx.x;
    const int lane = tid & 63, w = tid >> 6;
    const int wm = w >> 2, wn = w & 3;            // 2 x 4 wave grid
    const int m0 = blockIdx.y * 256, n0 = blockIdx.x * 256;
    const int fr = lane & 15, fk = (lane >> 4) * 8;
    const int NT = K >> 6;

    const int sprow = tid >> 3;                   // row within 64-row quarter
    const int scb0 = (tid & 7) * 16;              // byte col within 128B row
    const int wq = w * 512;                       // wave base (elements) in quarter

    f32x4 acc[8][4];
#pragma unroll
    for (int i = 0; i < 8; ++i)
#pragma unroll
        for (int j = 0; j < 4; ++j) acc[i][j] = (f32x4){0.f, 0.f, 0.f, 0.f};

    auto stage = [&](int dbuf, int isB, int qi, int kt) {
        const int prow = qi * 64 + sprow;
        const int sc = scb0 ^ (((prow >> 2) & 1) << 5);   // inverse swizzle
        const ushort* g = (isB ? (Bt + (size_t)(n0 + prow) * K)
                               : (A + (size_t)(m0 + prow) * K))
                          + (kt << 6) + (sc >> 1);
        gload_lds16(g, LDS + (isB ? 32768 : 0) + dbuf * 16384 + qi * 4096 + wq);
    };
    auto rdA = [&](int dbuf, int mi8, int ks) -> short8 {
        const int row = wm * 128 + mi8 * 16 + fr;
        int e = (row * 64 + ks * 32 + fk) ^ (((row >> 2) & 1) << 4);
        return *(const short8*)&LDS[dbuf * 16384 + e];
    };
    auto rdB = [&](int dbuf, int ni, int ks) -> short8 {
        const int row = wn * 64 + ni * 16 + fr;
        int e = (row * 64 + ks * 32 + fk) ^ (((row >> 2) & 1) << 4);
        return *(const short8*)&LDS[32768 + dbuf * 16384 + e];
    };

#pragma unroll
    for (int qi = 0; qi < 4; ++qi) stage(0, 0, qi, 0);
#pragma unroll
    for (int qi = 0; qi < 4; ++qi) stage(0, 1, qi, 0);

    for (int kt = 0; kt < NT; ++kt) {
        const int cur = kt & 1, nxt = cur ^ 1;
        const bool more = (kt + 1 < NT);
        short8 bfr[4], afr[4];

        // ---- phase 0
        if (more) {
            stage(nxt, 0, 0, kt + 1); stage(nxt, 0, 1, kt + 1);
            asm volatile("s_waitcnt vmcnt(2)" ::: "memory");
        } else {
            asm volatile("s_waitcnt vmcnt(0)" ::: "memory");
        }
        __builtin_amdgcn_s_barrier();
#pragma unroll
        for (int ni = 0; ni < 4; ++ni) bfr[ni] = rdB(cur, ni, 0);
#pragma unroll
        for (int mi = 0; mi < 4; ++mi) afr[mi] = rdA(cur, mi, 0);
        __builtin_amdgcn_s_setprio(1);
#pragma unroll
        for (int mi = 0; mi < 4; ++mi)
#pragma unroll
            for (int ni = 0; ni < 4; ++ni)
                acc[mi][ni] = __builtin_amdgcn_mfma_f32_16x16x32_bf16(
                    afr[mi], bfr[ni], acc[mi][ni], 0, 0, 0);
        __builtin_amdgcn_s_setprio(0);

        // ---- phase 1
        if (more) { stage(nxt, 0, 2, kt + 1); stage(nxt, 0, 3, kt + 1); }
#pragma unroll
        for (int mi = 0; mi < 4; ++mi) afr[mi] = rdA(cur, 4 + mi, 0);
        __builtin_amdgcn_s_setprio(1);
#pragma unroll
        for (int mi = 0; mi < 4; ++mi)
#pragma unroll
            for (int ni = 0; ni < 4; ++ni)
                acc[4 + mi][ni] = __builtin_amdgcn_mfma_f32_16x16x32_bf16(
                    afr[mi], bfr[ni], acc[4 + mi][ni], 0, 0, 0);
        __builtin_amdgcn_s_setprio(0);

        // ---- phase 2
        if (more) { stage(nxt, 1, 0, kt + 1); stage(nxt, 1, 1, kt + 1); }
#pragma unroll
        for (int ni = 0; ni < 4; ++ni) bfr[ni] = rdB(cur, ni, 1);
#pragma unroll
        for (int mi = 0; mi < 4; ++mi) afr[mi] = rdA(cur, mi, 1);
        __builtin_amdgcn_s_setprio(1);
#pragma unroll
        for (int mi = 0; mi < 4; ++mi)
#pragma unroll
            for (int ni = 0; ni < 4; ++ni)
                acc[mi][ni] = __builtin_amdgcn_mfma_f32_16x16x32_bf16(
                    afr[mi], bfr[ni], acc[mi][ni], 0, 0, 0);
        __builtin_amdgcn_s_setprio(0);

        // ---- phase 3
        if (more) { stage(nxt, 1, 2, kt + 1); stage(nxt, 1, 3, kt + 1); }
#pragma unroll
        for (int mi = 0; mi < 4; ++mi) afr[mi] = rdA(cur, 4 + mi, 1);
        __builtin_amdgcn_s_setprio(1);
#pragma unroll
        for (int mi = 0; mi < 4; ++mi)
#pragma unroll
            for (int ni = 0; ni < 4; ++ni)
                acc[4 + mi][ni] = __builtin_amdgcn_mfma_f32_16x16x32_bf16(
                    afr[mi], bfr[ni], acc[4 + mi][ni], 0, 0, 0);
        __builtin_amdgcn_s_setprio(0);

        __builtin_amdgcn_s_barrier();     // all waves done reading buf cur
    }

    // epilogue: bf16 C-tile via LDS
#pragma unroll
    for (int mi8 = 0; mi8 < 8; ++mi8)
#pragma unroll
        for (int r = 0; r < 4; ++r) {
            const int row = wm * 128 + mi8 * 16 + (lane >> 4) * 4 + r;
#pragma unroll
            for (int ni = 0; ni < 4; ++ni)
                LDS[row * 256 + wn * 64 + ni * 16 + fr] = f2bf(acc[mi8][ni][r]);
        }
    __builtin_amdgcn_s_barrier();
    const int frow = tid >> 5, fcb = (tid & 31) * 8;
#pragma unroll
    for (int it = 0; it < 16; ++it) {
        const int row = it * 16 + frow;
        ushort8 vv = *(const ushort8*)&LDS[row * 256 + fcb];
        *(ushort8*)&C[(size_t)(m0 + row) * N + n0 + fcb] = vv;
    }
}

// ---------------------------------------------------------------------------
// bf16 MFMA GEMM (128² 2-phase) — used for proj and classifier (fp32 out).
// ---------------------------------------------------------------------------
template <int RELU>
__global__ __launch_bounds__(256)
void gemm_bf16(const ushort* __restrict__ A, const ushort* __restrict__ Bt,
               float* __restrict__ C, int M, int N, int K)
{
    __shared__ __align__(16) ushort Sh[4][4096];   // [0..1]=A dbuf, [2..3]=B dbuf
    const int tid = threadIdx.x;
    const int lane = tid & 63, w = tid >> 6;
    const int m0 = blockIdx.y * 128, n0 = blockIdx.x * 128;
    const int srow = lane >> 2;
    const int skel = (lane & 3) * 8;
    const int wr = (w >> 1) * 64, wcol = (w & 1) * 64;
    const int fr = lane & 15, fk = (lane >> 4) * 8;

    f32x4 acc[4][4];
#pragma unroll
    for (int m = 0; m < 4; ++m)
#pragma unroll
        for (int n = 0; n < 4; ++n) acc[m][n] = (f32x4){0.f, 0.f, 0.f, 0.f};

#pragma unroll
    for (int q = 0; q < 2; ++q) {
        const int ch = w * 2 + q;
        gload_lds16(A + (size_t)(m0 + ch * 16 + srow) * K + skel, &Sh[0][ch * 512]);
        gload_lds16(Bt + (size_t)(n0 + ch * 16 + srow) * K + skel, &Sh[2][ch * 512]);
    }
    __syncthreads();

    int cur = 0;
    for (int k0 = 0; k0 < K; k0 += 32) {
        if (k0 + 32 < K) {
#pragma unroll
            for (int q = 0; q < 2; ++q) {
                const int ch = w * 2 + q;
                gload_lds16(A + (size_t)(m0 + ch * 16 + srow) * K + k0 + 32 + skel,
                            &Sh[cur ^ 1][ch * 512]);
                gload_lds16(Bt + (size_t)(n0 + ch * 16 + srow) * K + k0 + 32 + skel,
                            &Sh[2 + (cur ^ 1)][ch * 512]);
            }
        }
        short8 a[4], b[4];
#pragma unroll
        for (int m = 0; m < 4; ++m)
            a[m] = *(const short8*)&Sh[cur][(wr + m * 16 + fr) * 32 + fk];
#pragma unroll
        for (int n = 0; n < 4; ++n)
            b[n] = *(const short8*)&Sh[2 + cur][(wcol + n * 16 + fr) * 32 + fk];
#pragma unroll
        for (int m = 0; m < 4; ++m)
#pragma unroll
            for (int n = 0; n < 4; ++n)
                acc[m][n] = __builtin_amdgcn_mfma_f32_16x16x32_bf16(
                    a[m], b[n], acc[m][n], 0, 0, 0);
        __syncthreads();
        cur ^= 1;
    }
#pragma unroll
    for (int m = 0; m < 4; ++m) {
#pragma unroll
        for (int r = 0; r < 4; ++r) {
            const int row = m0 + wr + m * 16 + (lane >> 4) * 4 + r;
            const size_t rb = (size_t)row * N;
#pragma unroll
            for (int n = 0; n < 4; ++n) {
                float val = acc[m][n][r];
                if (RELU) val = fmaxf(val, 0.0f);
                C[rb + n0 + wcol + n * 16 + fr] = val;
            }
        }
    }
}

// ---------------------------------------------------------------------------
// Fused bidirectional SRU scan (U bf16, gate-interleaved cols).
// v4: asm-pinned double-buffer prefetch. ALL loop VMEM is inline asm so the
// vmcnt FIFO is fully controlled: per 16-step window, issue 16
// global_load_dwordx2 into the other buffer, s_waitcnt vmcnt(16) carried as
// "+v" deps on the consumed buffer (can't be hoisted/sunk), 16 asm stores.
// FIFO at consume-start: [fill16][stores16][newfill16] -> vmcnt(16) == buffer
// resident, next window's loads in flight. 256 blocks x 64 thr.
// ---------------------------------------------------------------------------
__global__ __launch_bounds__(64)
void sru_scan2(const ushort* __restrict__ U, const float* __restrict__ v,
               const float* __restrict__ bb, float* __restrict__ out)
{
    const int gidx = blockIdx.x * 64 + threadIdx.x;    // 0..16383
    const int dir = gidx >> 13;
    const int idx = gidx & 8191;
    const int j = idx & 511, b = idx >> 9;
    float vf = v[dir * 1024 + j],   vr = v[dir * 1024 + 512 + j];
    float bf_ = bb[dir * 1024 + j], br_ = bb[dir * 1024 + 512 + j];
    const size_t cb = (size_t)dir * 2048 + j * 4;
    const int co = dir * 512 + j;

    // Materialize scalar params, then drain all compiler vmem so no
    // compiler-inserted waitcnt (blind to our asm ops) fires mid-loop.
    asm volatile("" : "+v"(vf), "+v"(vr), "+v"(bf_), "+v"(br_));
    asm volatile("s_waitcnt vmcnt(0)" ::: "memory");

#define TT(q_) (dir ? (511 - (q_)) : (q_))
    float c = 0.0f;
    u32x2 A[16], B[16];

#define ISSUE(dst, s_)                                                         \
    asm volatile("global_load_dwordx2 %0, %1, off"                             \
                 : "=v"(dst)                                                   \
                 : "v"(U + (((size_t)(TT(s_) * 16 + b)) << 12) + cb)           \
                 : "memory")
#define FILL(BUF, wn_)                                                         \
    {                                                                          \
        _Pragma("unroll")                                                      \
        for (int q_ = 0; q_ < 16; ++q_) ISSUE(BUF[q_], (wn_) * 16 + q_);       \
    }
#define WAITBUF(BUF)                                                           \
    asm volatile("s_waitcnt vmcnt(16)"                                         \
                 : "+v"(BUF[0]), "+v"(BUF[1]), "+v"(BUF[2]), "+v"(BUF[3]),     \
                   "+v"(BUF[4]), "+v"(BUF[5]), "+v"(BUF[6]), "+v"(BUF[7]),     \
                   "+v"(BUF[8]), "+v"(BUF[9]), "+v"(BUF[10]), "+v"(BUF[11]),   \
                   "+v"(BUF[12]), "+v"(BUF[13]), "+v"(BUF[14]), "+v"(BUF[15])  \
                 :: "memory")
#define STEP(val, s_)                                                          \
    {                                                                          \
        const int t_ = TT(s_);                                                 \
        float xt = b2f(val[0] & 0xffffu);                                      \
        float fp = b2f(val[0] >> 16);                                          \
        float rp = b2f(val[1] & 0xffffu);                                      \
        float xp = b2f(val[1] >> 16);                                          \
        float f = sigmoidf_(fp + vf * c + bf_);                                \
        float r = sigmoidf_(rp + vr * c + br_);                                \
        c = fmaf(f, c - xt, xt);                                               \
        float h = fmaf(r, tanh_fast(c) - xp, xp);                              \
        asm volatile("global_store_dword %0, %1, off"                          \
                     :: "v"(out + (((size_t)(t_ * 16 + b)) << 10) + co),       \
                        "v"(h)                                                 \
                     : "memory");                                              \
    }

    FILL(A, 0);                                  // prologue: window 0 -> A
    for (int p = 0; p < 16; ++p) {
        const int s0 = p * 32;
        FILL(B, 2 * p + 1);                      // next window -> B
        WAITBUF(A);                              // A resident, B in flight
#pragma unroll
        for (int q = 0; q < 16; ++q) STEP(A[q], s0 + q);
        if (p < 15) FILL(A, 2 * p + 2);          // window after next -> A
        WAITBUF(B);
#pragma unroll
        for (int q = 0; q < 16; ++q) STEP(B[q], s0 + 16 + q);
    }
#undef STEP
#undef WAITBUF
#undef FILL
#undef ISSUE
#undef TT
}

// ---------------------------------------------------------------------------
// Final small GEMM (8192,512)@(512,29) with (t,b)->(b,t) output scatter.
// ---------------------------------------------------------------------------
__global__ __launch_bounds__(256)
void cls_out(const float* __restrict__ h1, const float* __restrict__ W2,
             float* __restrict__ out)
{
    const int gidx = blockIdx.x * 256 + threadIdx.x;
    const int n = gidx & 31, m = gidx >> 5;
    if (n >= 29) return;
    const float4* hr = (const float4*)(h1 + (size_t)m * 512);
    float acc = 0.0f;
    for (int k4 = 0; k4 < 128; ++k4) {
        float4 hv = hr[k4];
        const float* wp = W2 + (size_t)(k4 * 4) * 29 + n;
        acc = fmaf(hv.x, wp[0],  acc);
        acc = fmaf(hv.y, wp[29], acc);
        acc = fmaf(hv.z, wp[58], acc);
        acc = fmaf(hv.w, wp[87], acc);
    }
    const int t = m >> 4, b = m & 15;
    out[((size_t)b * 512 + t) * 29 + n] = acc;
}

// ---------------------------------------------------------------------------
// Host orchestration. Workspace layout identical to rounds 7-10.
// ---------------------------------------------------------------------------
extern "C" void kernel_launch(void* const* d_in, const int* in_sizes, int n_in,
                              void* d_out, int out_size, void* d_ws, size_t ws_size,
                              hipStream_t stream)
{
    (void)in_sizes; (void)n_in; (void)out_size; (void)ws_size;
    const float* x      = (const float*)d_in[0];
    const float* cnn_w  = (const float*)d_in[1];
    const float* cnn_b  = (const float*)d_in[2];
    const float* c1w    = (const float*)d_in[3];
    const float* c1b    = (const float*)d_in[4];
    const float* bn1g   = (const float*)d_in[5];
    const float* bn1b   = (const float*)d_in[6];
    const float* bn1m   = (const float*)d_in[7];
    const float* bn1v   = (const float*)d_in[8];
    const float* c2w    = (const float*)d_in[9];
    const float* c2b    = (const float*)d_in[10];
    const float* bn2g   = (const float*)d_in[11];
    const float* bn2b   = (const float*)d_in[12];
    const float* bn2m   = (const float*)d_in[13];
    const float* bn2v   = (const float*)d_in[14];
    const float* projW  = (const float*)d_in[15];
    const float* sruW   = (const float*)d_in[16];
    const float* sruV   = (const float*)d_in[17];
    const float* sruB   = (const float*)d_in[18];
    const float* sruLNg = (const float*)d_in[19];
    const float* sruLNb = (const float*)d_in[20];
    const float* clsLNg = (const float*)d_in[21];
    const float* clsLNb = (const float*)d_in[22];
    const float* W1     = (const float*)d_in[23];
    const float* W2     = (const float*)d_in[24];
    float* out = (float*)d_out;
    float* ws  = (float*)d_ws;

    ushort* Xhi = (ushort*)ws;
    ushort* Thi = Xhi + PADN;
    ushort* convw_hi = (ushort*)(ws + 34742016);
    ushort* convw_lo = convw_hi + 55296;
    ushort* xrow_bf  = (ushort*)(ws + 34865152);   // [8192][2048]
    ushort* xn_bf    = (ushort*)(ws + 43253760);   // [8192][1024]
    ushort* Ubuf     = (ushort*)ws;                // [8192][4096]
    float*  xch      = ws + 16777216;              // [8192][1024] fp32
    ushort* proj_bt  = (ushort*)(ws + 25165824);   // [1024][2048]
    ushort* sru_bt   = (ushort*)(ws + 26214400);   // 8 x [2048][1024]
    ushort* w1t      = (ushort*)(ws + 34603008);   // [512][1024]
    float*  h1       = ws;                         // [8192][512] fp32

    dim3 blk(256);

    // --- conv phase ---
    ring_zero<<<1160, blk, 0, stream>>>(Xhi, Thi);
    conv_wprep<<<6, blk, 0, stream>>>(c1w, c2w, convw_hi, convw_lo);
    conv_stem_p<<<dim3(8, 16, 16), blk, 0, stream>>>(x, cnn_w, cnn_b, Xhi);
    for (int i = 0; i < 3; ++i) {
        const int l1 = 2 * i, l2 = 2 * i + 1;
        conv_mfma<0><<<dim3(4, 16, 16), blk, 0, stream>>>(
            Xhi, convw_hi + l1 * 9216, convw_lo + l1 * 9216,
            bn1g + i * 32, bn1b + i * 32, bn1m + i * 32, bn1v + i * 32,
            c1b + i * 32, nullptr, Thi);
        conv_mfma<1><<<dim3(4, 16, 16), blk, 0, stream>>>(
            Thi, convw_hi + l2 * 9216, convw_lo + l2 * 9216,
            bn2g + i * 32, bn2b + i * 32, bn2m + i * 32, bn2v + i * 32,
            c2b + i * 32, Xhi, Xhi);
    }

    // --- GEMM weight conversion (SRU batched via z) ---
    wconv_t<<<dim3(32, 16, 1), blk, 0, stream>>>(projW, proj_bt, 2048, 1024, 0, 0, 0);
    wconv_t<<<dim3(16, 32, 8), blk, 0, stream>>>(sruW, sru_bt, 1024, 2048, 1,
                                                 2097152, 2097152);
    wconv_t<<<dim3(16, 8, 1), blk, 0, stream>>>(W1, w1t, 1024, 512, 0, 0, 0);

    // --- gather to bf16 rows ---
    gather_pad<<<dim3(32, 16), blk, 0, stream>>>(Xhi, xrow_bf);

    // --- proj GEMM: (8192,2048)@(2048,1024) -> xch fp32 ---
    gemm_bf16<0><<<dim3(8, 64), blk, 0, stream>>>(
        xrow_bf, proj_bt, xch, 8192, 1024, 2048);

    // --- SRU layers ---
    for (int l = 0; l < 4; ++l) {
        layernorm1024_bf<<<8192, blk, 0, stream>>>(
            xch, sruLNg + l * 1024, sruLNb + l * 1024, xn_bf);
        gemm256_bf16<<<dim3(16, 32), dim3(512), 0, stream>>>(
            xn_bf, sru_bt + (size_t)l * 4194304, Ubuf, 8192, 4096, 1024);
        sru_scan2<<<256, dim3(64), 0, stream>>>(
            Ubuf, sruV + l * 2048, sruB + l * 2048, xch);
    }

    // --- classifier ---
    layernorm1024_bf<<<8192, blk, 0, stream>>>(xch, clsLNg, clsLNb, xn_bf);
    gemm_bf16<1><<<dim3(4, 64), blk, 0, stream>>>(
        xn_bf, w1t, h1, 8192, 512, 1024);
    cls_out<<<1024, blk, 0, stream>>>(h1, W2, out);
}

// Round 12
// 813.105 us; speedup vs baseline: 1.1749x; 1.1513x over previous
//
#include <hip/hip_runtime.h>
#include <cstddef>

#define DEVFN __device__ __forceinline__

typedef __attribute__((ext_vector_type(8))) short short8;          // 8 bf16
typedef __attribute__((ext_vector_type(8))) unsigned short ushort8;
typedef __attribute__((ext_vector_type(4))) float f32x4;           // MFMA acc

DEVFN float sigmoidf_(float x) { return 1.0f / (1.0f + __expf(-x)); }
DEVFN float tanh_fast(float x) {
    float e = __expf(2.0f * x);
    return 1.0f - 2.0f / (e + 1.0f);
}
DEVFN unsigned short f2bf(float f) {            // round-to-nearest-even
    unsigned int u = __float_as_uint(f);
    return (unsigned short)((u + 0x7FFFu + ((u >> 16) & 1u)) >> 16);
}
DEVFN float b2f(unsigned int bits) { return __uint_as_float(bits << 16); }

DEVFN void gload_lds16(const ushort* g, ushort* l) {
    __builtin_amdgcn_global_load_lds(
        (const __attribute__((address_space(1))) unsigned int*)g,
        (__attribute__((address_space(3))) unsigned int*)l, 16, 0, 0);
}

// Padded NHWC geometry: [16 b][66 hs][514 ws][32 c], hs = h+1, ws = w+1.
#define PADN 17371008u

// ---------------------------------------------------------------------------
// Zero the padding ring of the 2 padded NHWC tensors.
// ---------------------------------------------------------------------------
__global__ __launch_bounds__(256)
void ring_zero(ushort* A, ushort* B)
{
    int idx = blockIdx.x * 256 + threadIdx.x;
    if (idx >= 296960) return;
    size_t uoff;
    if (idx < 263168) {                       // rows hs in {0,65}
        int b = idx / 16448, r = idx % 16448;
        int hs = (r < 8224) ? 0 : 65;
        int o = (r < 8224) ? r : r - 8224;
        uoff = (((size_t)(b * 66 + hs) * 514) * 32 + (size_t)o * 2) >> 1;
    } else {                                  // cols ws in {0,513}
        int j = idx - 263168;
        int b = j / 2112, r = j % 2112;
        int hs = r >> 5, e = r & 31;
        int wsp = (e < 16) ? 0 : 513;
        int c2 = e & 15;
        uoff = (((size_t)(b * 66 + hs) * 514 + wsp) * 32 + (size_t)c2 * 2) >> 1;
    }
    ((uint*)A)[uoff] = 0; ((uint*)B)[uoff] = 0;
}

// ---------------------------------------------------------------------------
// Conv-weight prep: [co][ci][3][3] fp32 -> [lay][q][co][ci] bf16 hi/lo.
// ---------------------------------------------------------------------------
__global__ __launch_bounds__(256)
void conv_wprep(const float* __restrict__ c1w, const float* __restrict__ c2w,
                ushort* __restrict__ whi, ushort* __restrict__ wlo)
{
    const int lay = blockIdx.x;               // 0..5
    const int i = lay >> 1;
    const float* src = (lay & 1) ? (c2w + i * 9216) : (c1w + i * 9216);
    for (int e = threadIdx.x; e < 9216; e += 256) {
        int co = e / 288, rem = e % 288, ci = rem / 9, q = rem % 9;
        float v = src[e];
        unsigned short hi = f2bf(v);
        unsigned short lo = f2bf(v - b2f(hi));
        int dst = ((lay * 9 + q) * 32 + co) * 32 + ci;
        whi[dst] = hi; wlo[dst] = lo;
    }
}

// ---------------------------------------------------------------------------
// Conv stem -> padded NHWC bf16. x (16,1,128,1024), stride 2, pad 1.
// ---------------------------------------------------------------------------
__global__ __launch_bounds__(256)
void conv_stem_p(const float* __restrict__ x, const float* __restrict__ w,
                 const float* __restrict__ cb, ushort* __restrict__ Xhi)
{
    const int b = blockIdx.z;
    const int h = blockIdx.y * 4 + (threadIdx.x >> 6);
    const int wc = blockIdx.x * 64 + (threadIdx.x & 63);
    float iv[9];
#pragma unroll
    for (int kh = 0; kh < 3; ++kh)
#pragma unroll
        for (int kw = 0; kw < 3; ++kw) {
            int ih = 2 * h - 1 + kh, iw = 2 * wc - 1 + kw;
            iv[kh * 3 + kw] = (ih >= 0 && ih < 128 && iw >= 0 && iw < 1024)
                ? x[(size_t)b * 131072 + (size_t)ih * 1024 + iw] : 0.0f;
        }
    unsigned short hi[32];
#pragma unroll
    for (int co = 0; co < 32; ++co) {
        const float* wp = w + co * 9;
        float a = cb[co];
#pragma unroll
        for (int q = 0; q < 9; ++q) a = fmaf(iv[q], wp[q], a);
        hi[co] = f2bf(a);
    }
    const size_t o = ((size_t)(b * 66 + h + 1) * 514 + wc + 1) * 32;
#pragma unroll
    for (int v = 0; v < 4; ++v) {
        ushort8 uh;
#pragma unroll
        for (int e = 0; e < 8; ++e) uh[e] = hi[v * 8 + e];
        *(ushort8*)(Xhi + o + v * 8) = uh;
    }
}

// ---------------------------------------------------------------------------
// MFMA implicit-GEMM conv 3x3 (32->32) + BN (+res) + ReLU. (round-8 version)
// ---------------------------------------------------------------------------
template <int RES>
__global__ __launch_bounds__(256)
void conv_mfma(const ushort* __restrict__ Phi,
               const ushort* __restrict__ gwhi, const ushort* __restrict__ gwlo,
               const float* __restrict__ g, const float* __restrict__ bbn,
               const float* __restrict__ mn, const float* __restrict__ vn,
               const float* __restrict__ cbv,
               const ushort* __restrict__ Rhi, ushort* __restrict__ Ohi)
{
    __shared__ __align__(16) ushort Wsh[9216], Wsl[9216];
    const int tid = threadIdx.x, lane = tid & 63, wv = tid >> 6;
    const int b = blockIdx.z, h0 = blockIdx.y * 4, w0 = blockIdx.x * 128;

    for (int i = tid; i < 1152; i += 256) {
        ((uint4*)Wsh)[i] = ((const uint4*)gwhi)[i];
        ((uint4*)Wsl)[i] = ((const uint4*)gwlo)[i];
    }
    __syncthreads();

    const int wr = wv * 32;
    const int fr = lane & 15, fk = (lane >> 4) * 8;
    const int lo0 = (wr + fr) * 32 + fk;
    const int lo1 = (wr + 16 + fr) * 32 + fk;

    float sc[2], sh[2];
#pragma unroll
    for (int n = 0; n < 2; ++n) {
        const int co = n * 16 + fr;
        sc[n] = g[co] * rsqrtf(vn[co] + 1e-5f);
        sh[n] = bbn[co] - mn[co] * sc[n] + cbv[co] * sc[n];
    }

    short8 A[3][2][3];
#define LOADROW(SL, PR)                                                        \
    {                                                                          \
        const size_t rb_ = ((size_t)(b * 66 + (PR)) * 514 + w0) * 32;          \
        _Pragma("unroll")                                                      \
        for (int kw_ = 0; kw_ < 3; ++kw_) {                                    \
            A[SL][0][kw_] = *(const short8*)(Phi + rb_ + kw_ * 32 + lo0);      \
            A[SL][1][kw_] = *(const short8*)(Phi + rb_ + kw_ * 32 + lo1);      \
        }                                                                      \
    }

    LOADROW(0, h0);
    LOADROW(1, h0 + 1);

#pragma unroll
    for (int hh = 0; hh < 4; ++hh) {
        LOADROW((hh + 2) % 3, h0 + hh + 2);
        f32x4 acc[2][2];
#pragma unroll
        for (int m = 0; m < 2; ++m)
#pragma unroll
            for (int n = 0; n < 2; ++n) acc[m][n] = (f32x4){0.f, 0.f, 0.f, 0.f};
#pragma unroll
        for (int kh = 0; kh < 3; ++kh) {
            const int sl = (hh + kh) % 3;
#pragma unroll
            for (int kw = 0; kw < 3; ++kw) {
                const int q = kh * 3 + kw;
                short8 ah0 = A[sl][0][kw];
                short8 ah1 = A[sl][1][kw];
                short8 bh0 = *(const short8*)&Wsh[q * 1024 + fr * 32 + fk];
                short8 bh1 = *(const short8*)&Wsh[q * 1024 + (16 + fr) * 32 + fk];
                short8 bl0 = *(const short8*)&Wsl[q * 1024 + fr * 32 + fk];
                short8 bl1 = *(const short8*)&Wsl[q * 1024 + (16 + fr) * 32 + fk];
                acc[0][0] = __builtin_amdgcn_mfma_f32_16x16x32_bf16(ah0, bh0, acc[0][0], 0, 0, 0);
                acc[0][1] = __builtin_amdgcn_mfma_f32_16x16x32_bf16(ah0, bh1, acc[0][1], 0, 0, 0);
                acc[1][0] = __builtin_amdgcn_mfma_f32_16x16x32_bf16(ah1, bh0, acc[1][0], 0, 0, 0);
                acc[1][1] = __builtin_amdgcn_mfma_f32_16x16x32_bf16(ah1, bh1, acc[1][1], 0, 0, 0);
                acc[0][0] = __builtin_amdgcn_mfma_f32_16x16x32_bf16(ah0, bl0, acc[0][0], 0, 0, 0);
                acc[0][1] = __builtin_amdgcn_mfma_f32_16x16x32_bf16(ah0, bl1, acc[0][1], 0, 0, 0);
                acc[1][0] = __builtin_amdgcn_mfma_f32_16x16x32_bf16(ah1, bl0, acc[1][0], 0, 0, 0);
                acc[1][1] = __builtin_amdgcn_mfma_f32_16x16x32_bf16(ah1, bl1, acc[1][1], 0, 0, 0);
            }
        }
#pragma unroll
        for (int m = 0; m < 2; ++m)
#pragma unroll
            for (int r = 0; r < 4; ++r) {
                const int wl = wr + m * 16 + (lane >> 4) * 4 + r;
                const size_t oidx =
                    ((size_t)(b * 66 + h0 + hh + 1) * 514 + w0 + wl + 1) * 32;
#pragma unroll
                for (int n = 0; n < 2; ++n) {
                    const int co = n * 16 + fr;
                    float val = acc[m][n][r] * sc[n] + sh[n];
                    if (RES) val += b2f(Rhi[oidx + co]);
                    val = fmaxf(val, 0.0f);
                    Ohi[oidx + co] = f2bf(val);
                }
            }
    }
#undef LOADROW
}

// ---------------------------------------------------------------------------
// Gather: padded NHWC -> xrow_bf[(w*16+b)][c*64+h]  (8192 x 2048 bf16)
// ---------------------------------------------------------------------------
__global__ __launch_bounds__(256)
void gather_pad(const ushort* __restrict__ Xhi, ushort* __restrict__ xrow)
{
    __shared__ ushort tile[64 * 16 * 32];        // [h][wl][c], 64 KB
    const int b = blockIdx.y, w0 = blockIdx.x * 16;
    for (int k = threadIdx.x; k < 4096; k += 256) {
        int h = k >> 6, rem = k & 63, wl = rem >> 2, c8 = (rem & 3) * 8;
        const ushort* src = Xhi + ((size_t)(b * 66 + h + 1) * 514 + w0 + 1 + wl) * 32 + c8;
        *(ushort8*)&tile[(h * 16 + wl) * 32 + c8] = *(const ushort8*)src;
    }
    __syncthreads();
    for (int k = threadIdx.x; k < 4096; k += 256) {
        int wl = k >> 8, rem = k & 255, c = rem >> 3, h8 = (rem & 7) * 8;
        ushort8 v;
#pragma unroll
        for (int e = 0; e < 8; ++e) v[e] = tile[((h8 + e) * 16 + wl) * 32 + c];
        *(ushort8*)&xrow[((size_t)(w0 + wl) * 16 + b) * 2048 + c * 64 + h8] = v;
    }
}

// ---------------------------------------------------------------------------
// Weight transpose+convert: W [K][N] fp32 -> Bt [N'][K] bf16.
// perm=1 (SRU): within N=2048, n = gate*512+j -> n' = j*4+gate.
// ---------------------------------------------------------------------------
__global__ __launch_bounds__(256)
void wconv_t(const float* __restrict__ W, ushort* __restrict__ Bt,
             int K, int N, int perm, size_t wstr, size_t btstr)
{
    __shared__ float tile[64][65];
    const float* Wp = W + (size_t)blockIdx.z * wstr;
    ushort* Btp = Bt + (size_t)blockIdx.z * btstr;
    const int k0 = blockIdx.x * 64;
    const int n0 = blockIdx.y * 64;
#pragma unroll
    for (int p = 0; p < 16; ++p) {
        int idx = p * 256 + threadIdx.x;
        int kl = idx >> 6, nl = idx & 63;
        tile[kl][nl] = Wp[(size_t)(k0 + kl) * N + n0 + nl];
    }
    __syncthreads();
#pragma unroll
    for (int p = 0; p < 16; ++p) {
        int idx = p * 256 + threadIdx.x;
        int nl = idx >> 6, kl = idx & 63;
        int n = n0 + nl;
        int row = perm ? ((n & 511) * 4 + (n >> 9)) : n;
        Btp[(size_t)row * K + k0 + kl] = f2bf(tile[kl][nl]);
    }
}

// ---------------------------------------------------------------------------
// LayerNorm over last dim (1024), rows = 8192, fp32 in -> bf16 out.
// (used only for the proj output, layer 0)
// ---------------------------------------------------------------------------
__global__ __launch_bounds__(256)
void layernorm1024_bf(const float* __restrict__ x, const float* __restrict__ g,
                      const float* __restrict__ b, ushort* __restrict__ y)
{
    const size_t row = blockIdx.x;
    const float4 v = ((const float4*)(x + row * 1024))[threadIdx.x];
    float s = v.x + v.y + v.z + v.w;
    float s2 = v.x * v.x + v.y * v.y + v.z * v.z + v.w * v.w;
#pragma unroll
    for (int off = 32; off; off >>= 1) {
        s += __shfl_down(s, off);
        s2 += __shfl_down(s2, off);
    }
    __shared__ float red[2][4];
    int wid = threadIdx.x >> 6, lane = threadIdx.x & 63;
    if (lane == 0) { red[0][wid] = s; red[1][wid] = s2; }
    __syncthreads();
    s = red[0][0] + red[0][1] + red[0][2] + red[0][3];
    s2 = red[1][0] + red[1][1] + red[1][2] + red[1][3];
    float mu = s * (1.0f / 1024.0f);
    float var = s2 * (1.0f / 1024.0f) - mu * mu;
    float rstd = rsqrtf(var + 1e-5f);
    float4 gv = ((const float4*)g)[threadIdx.x];
    float4 bv = ((const float4*)b)[threadIdx.x];
    ushort4 o;
    o.x = f2bf((v.x - mu) * rstd * gv.x + bv.x);
    o.y = f2bf((v.y - mu) * rstd * gv.y + bv.y);
    o.z = f2bf((v.z - mu) * rstd * gv.z + bv.z);
    o.w = f2bf((v.w - mu) * rstd * gv.w + bv.w);
    ((ushort4*)(y + row * 1024))[threadIdx.x] = o;
}

// ---------------------------------------------------------------------------
// Fused h-compute + LayerNorm.  Row r = t*16+b (8192 rows).
// h = r_g*tanh(c_t) + (1-r_g)*xp,  r_g = sigmoid(rp + vr*c_{prev} + br)
// where c_prev = chain carry BEFORE this step (row r-16 for dir0, r+16 for
// dir1, 0 at the chain start).  Then LayerNorm(h) -> bf16.
// ---------------------------------------------------------------------------
__global__ __launch_bounds__(256)
void lnh(const float* __restrict__ cbuf, const ushort* __restrict__ Uo,
         const float* __restrict__ v, const float* __restrict__ bb,
         const float* __restrict__ g, const float* __restrict__ be,
         ushort* __restrict__ y)
{
    const int r = blockIdx.x, t = r >> 4;
    const int tid = threadIdx.x, dir = tid >> 7;
    const int jj = (tid * 4) & 511;
    float4 cc = *(const float4*)(cbuf + (size_t)r * 1024 + tid * 4);
    const int pr = dir ? (t == 511 ? -1 : r + 16) : (t == 0 ? -1 : r - 16);
    float4 cp = {0.f, 0.f, 0.f, 0.f};
    if (pr >= 0) cp = *(const float4*)(cbuf + (size_t)pr * 1024 + tid * 4);
    ushort8 u = *(const ushort8*)(Uo + (size_t)r * 2048 + dir * 1024 + jj * 2);
    float4 vr = *(const float4*)(v + dir * 1024 + 512 + jj);
    float4 br = *(const float4*)(bb + dir * 1024 + 512 + jj);
    float h[4];
    const float cpe[4] = {cp.x, cp.y, cp.z, cp.w};
    const float cce[4] = {cc.x, cc.y, cc.z, cc.w};
    const float vre[4] = {vr.x, vr.y, vr.z, vr.w};
    const float bre[4] = {br.x, br.y, br.z, br.w};
#pragma unroll
    for (int e = 0; e < 4; ++e) {
        float rp = b2f(u[2 * e]);
        float xp = b2f(u[2 * e + 1]);
        float rg = sigmoidf_(rp + vre[e] * cpe[e] + bre[e]);
        h[e] = fmaf(rg, tanh_fast(cce[e]) - xp, xp);
    }
    float s = h[0] + h[1] + h[2] + h[3];
    float s2 = h[0] * h[0] + h[1] * h[1] + h[2] * h[2] + h[3] * h[3];
#pragma unroll
    for (int off = 32; off; off >>= 1) {
        s += __shfl_down(s, off);
        s2 += __shfl_down(s2, off);
    }
    __shared__ float red[2][4];
    int wid = tid >> 6, lane = tid & 63;
    if (lane == 0) { red[0][wid] = s; red[1][wid] = s2; }
    __syncthreads();
    s = red[0][0] + red[0][1] + red[0][2] + red[0][3];
    s2 = red[1][0] + red[1][1] + red[1][2] + red[1][3];
    float mu = s * (1.0f / 1024.0f);
    float var = s2 * (1.0f / 1024.0f) - mu * mu;
    float rstd = rsqrtf(var + 1e-5f);
    float4 gv = ((const float4*)g)[tid];
    float4 bv = ((const float4*)be)[tid];
    ushort4 o;
    o.x = f2bf((h[0] - mu) * rstd * gv.x + bv.x);
    o.y = f2bf((h[1] - mu) * rstd * gv.y + bv.y);
    o.z = f2bf((h[2] - mu) * rstd * gv.z + bv.z);
    o.w = f2bf((h[3] - mu) * rstd * gv.w + bv.w);
    ((ushort4*)(y + (size_t)r * 1024))[tid] = o;
}

// ---------------------------------------------------------------------------
// 256x256 8-phase bf16 GEMM (m201 template), SRU variant: epilogue splits the
// gate-interleaved output into Uchain (xt,fp) and Uout (rp,xp), each
// [8192][2048] ushorts with col = dir*1024 + j*2 + {0,1}.
// ---------------------------------------------------------------------------
__global__ __launch_bounds__(512, 2)
void gemm256_bf16(const ushort* __restrict__ A, const ushort* __restrict__ Bt,
                  ushort* __restrict__ Uc, ushort* __restrict__ Uo,
                  int M, int N, int K)
{
    __shared__ __align__(16) ushort LDS[65536];   // A:[2][16384], B:+32768
    const int tid = threadIdx.x;
    const int lane = tid & 63, w = tid >> 6;
    const int wm = w >> 2, wn = w & 3;            // 2 x 4 wave grid
    const int m0 = blockIdx.y * 256, n0 = blockIdx.x * 256;
    const int fr = lane & 15, fk = (lane >> 4) * 8;
    const int NT = K >> 6;

    const int sprow = tid >> 3;                   // row within 64-row quarter
    const int scb0 = (tid & 7) * 16;              // byte col within 128B row
    const int wq = w * 512;                       // wave base (elements) in quarter

    f32x4 acc[8][4];
#pragma unroll
    for (int i = 0; i < 8; ++i)
#pragma unroll
        for (int j = 0; j < 4; ++j) acc[i][j] = (f32x4){0.f, 0.f, 0.f, 0.f};

    auto stage = [&](int dbuf, int isB, int qi, int kt) {
        const int prow = qi * 64 + sprow;
        const int sc = scb0 ^ (((prow >> 2) & 1) << 5);   // inverse swizzle
        const ushort* g = (isB ? (Bt + (size_t)(n0 + prow) * K)
                               : (A + (size_t)(m0 + prow) * K))
                          + (kt << 6) + (sc >> 1);
        gload_lds16(g, LDS + (isB ? 32768 : 0) + dbuf * 16384 + qi * 4096 + wq);
    };
    auto rdA = [&](int dbuf, int mi8, int ks) -> short8 {
        const int row = wm * 128 + mi8 * 16 + fr;
        int e = (row * 64 + ks * 32 + fk) ^ (((row >> 2) & 1) << 4);
        return *(const short8*)&LDS[dbuf * 16384 + e];
    };
    auto rdB = [&](int dbuf, int ni, int ks) -> short8 {
        const int row = wn * 64 + ni * 16 + fr;
        int e = (row * 64 + ks * 32 + fk) ^ (((row >> 2) & 1) << 4);
        return *(const short8*)&LDS[32768 + dbuf * 16384 + e];
    };

#pragma unroll
    for (int qi = 0; qi < 4; ++qi) stage(0, 0, qi, 0);
#pragma unroll
    for (int qi = 0; qi < 4; ++qi) stage(0, 1, qi, 0);

    for (int kt = 0; kt < NT; ++kt) {
        const int cur = kt & 1, nxt = cur ^ 1;
        const bool more = (kt + 1 < NT);
        short8 bfr[4], afr[4];

        // ---- phase 0
        if (more) {
            stage(nxt, 0, 0, kt + 1); stage(nxt, 0, 1, kt + 1);
            asm volatile("s_waitcnt vmcnt(2)" ::: "memory");
        } else {
            asm volatile("s_waitcnt vmcnt(0)" ::: "memory");
        }
        __builtin_amdgcn_s_barrier();
#pragma unroll
        for (int ni = 0; ni < 4; ++ni) bfr[ni] = rdB(cur, ni, 0);
#pragma unroll
        for (int mi = 0; mi < 4; ++mi) afr[mi] = rdA(cur, mi, 0);
        __builtin_amdgcn_s_setprio(1);
#pragma unroll
        for (int mi = 0; mi < 4; ++mi)
#pragma unroll
            for (int ni = 0; ni < 4; ++ni)
                acc[mi][ni] = __builtin_amdgcn_mfma_f32_16x16x32_bf16(
                    afr[mi], bfr[ni], acc[mi][ni], 0, 0, 0);
        __builtin_amdgcn_s_setprio(0);

        // ---- phase 1
        if (more) { stage(nxt, 0, 2, kt + 1); stage(nxt, 0, 3, kt + 1); }
#pragma unroll
        for (int mi = 0; mi < 4; ++mi) afr[mi] = rdA(cur, 4 + mi, 0);
        __builtin_amdgcn_s_setprio(1);
#pragma unroll
        for (int mi = 0; mi < 4; ++mi)
#pragma unroll
            for (int ni = 0; ni < 4; ++ni)
                acc[4 + mi][ni] = __builtin_amdgcn_mfma_f32_16x16x32_bf16(
                    afr[mi], bfr[ni], acc[4 + mi][ni], 0, 0, 0);
        __builtin_amdgcn_s_setprio(0);

        // ---- phase 2
        if (more) { stage(nxt, 1, 0, kt + 1); stage(nxt, 1, 1, kt + 1); }
#pragma unroll
        for (int ni = 0; ni < 4; ++ni) bfr[ni] = rdB(cur, ni, 1);
#pragma unroll
        for (int mi = 0; mi < 4; ++mi) afr[mi] = rdA(cur, mi, 1);
        __builtin_amdgcn_s_setprio(1);
#pragma unroll
        for (int mi = 0; mi < 4; ++mi)
#pragma unroll
            for (int ni = 0; ni < 4; ++ni)
                acc[mi][ni] = __builtin_amdgcn_mfma_f32_16x16x32_bf16(
                    afr[mi], bfr[ni], acc[mi][ni], 0, 0, 0);
        __builtin_amdgcn_s_setprio(0);

        // ---- phase 3
        if (more) { stage(nxt, 1, 2, kt + 1); stage(nxt, 1, 3, kt + 1); }
#pragma unroll
        for (int mi = 0; mi < 4; ++mi) afr[mi] = rdA(cur, 4 + mi, 1);
        __builtin_amdgcn_s_setprio(1);
#pragma unroll
        for (int mi = 0; mi < 4; ++mi)
#pragma unroll
            for (int ni = 0; ni < 4; ++ni)
                acc[4 + mi][ni] = __builtin_amdgcn_mfma_f32_16x16x32_bf16(
                    afr[mi], bfr[ni], acc[4 + mi][ni], 0, 0, 0);
        __builtin_amdgcn_s_setprio(0);

        __builtin_amdgcn_s_barrier();     // all waves done reading buf cur
    }

    // epilogue: bf16 C-tile via LDS, then split-store to Uchain/Uout
#pragma unroll
    for (int mi8 = 0; mi8 < 8; ++mi8)
#pragma unroll
        for (int r = 0; r < 4; ++r) {
            const int row = wm * 128 + mi8 * 16 + (lane >> 4) * 4 + r;
#pragma unroll
            for (int ni = 0; ni < 4; ++ni)
                LDS[row * 256 + wn * 64 + ni * 16 + fr] = f2bf(acc[mi8][ni][r]);
        }
    __builtin_amdgcn_s_barrier();
    const int frow = tid >> 5, fcb = (tid & 31) * 8;
    const int g0 = n0 + fcb;
    const int dirq = g0 >> 11, j0 = (g0 & 2047) >> 2;
    const size_t cbase = (size_t)dirq * 1024 + j0 * 2;
#pragma unroll
    for (int it = 0; it < 16; ++it) {
        const int row = it * 16 + frow;
        ushort8 vv = *(const ushort8*)&LDS[row * 256 + fcb];
        uint2 ch, uo;
        ch.x = (uint)vv[0] | ((uint)vv[1] << 16);
        ch.y = (uint)vv[4] | ((uint)vv[5] << 16);
        uo.x = (uint)vv[2] | ((uint)vv[3] << 16);
        uo.y = (uint)vv[6] | ((uint)vv[7] << 16);
        const size_t rb = (size_t)(m0 + row) * 2048 + cbase;
        *(uint2*)&Uc[rb] = ch;
        *(uint2*)&Uo[rb] = uo;
    }
}

// ---------------------------------------------------------------------------
// bf16 MFMA GEMM (128² 2-phase) — used for proj and classifier (fp32 out).
// ---------------------------------------------------------------------------
template <int RELU>
__global__ __launch_bounds__(256)
void gemm_bf16(const ushort* __restrict__ A, const ushort* __restrict__ Bt,
               float* __restrict__ C, int M, int N, int K)
{
    __shared__ __align__(16) ushort Sh[4][4096];   // [0..1]=A dbuf, [2..3]=B dbuf
    const int tid = threadIdx.x;
    const int lane = tid & 63, w = tid >> 6;
    const int m0 = blockIdx.y * 128, n0 = blockIdx.x * 128;
    const int srow = lane >> 2;
    const int skel = (lane & 3) * 8;
    const int wr = (w >> 1) * 64, wcol = (w & 1) * 64;
    const int fr = lane & 15, fk = (lane >> 4) * 8;

    f32x4 acc[4][4];
#pragma unroll
    for (int m = 0; m < 4; ++m)
#pragma unroll
        for (int n = 0; n < 4; ++n) acc[m][n] = (f32x4){0.f, 0.f, 0.f, 0.f};

#pragma unroll
    for (int q = 0; q < 2; ++q) {
        const int ch = w * 2 + q;
        gload_lds16(A + (size_t)(m0 + ch * 16 + srow) * K + skel, &Sh[0][ch * 512]);
        gload_lds16(Bt + (size_t)(n0 + ch * 16 + srow) * K + skel, &Sh[2][ch * 512]);
    }
    __syncthreads();

    int cur = 0;
    for (int k0 = 0; k0 < K; k0 += 32) {
        if (k0 + 32 < K) {
#pragma unroll
            for (int q = 0; q < 2; ++q) {
                const int ch = w * 2 + q;
                gload_lds16(A + (size_t)(m0 + ch * 16 + srow) * K + k0 + 32 + skel,
                            &Sh[cur ^ 1][ch * 512]);
                gload_lds16(Bt + (size_t)(n0 + ch * 16 + srow) * K + k0 + 32 + skel,
                            &Sh[2 + (cur ^ 1)][ch * 512]);
            }
        }
        short8 a[4], b[4];
#pragma unroll
        for (int m = 0; m < 4; ++m)
            a[m] = *(const short8*)&Sh[cur][(wr + m * 16 + fr) * 32 + fk];
#pragma unroll
        for (int n = 0; n < 4; ++n)
            b[n] = *(const short8*)&Sh[2 + cur][(wcol + n * 16 + fr) * 32 + fk];
#pragma unroll
        for (int m = 0; m < 4; ++m)
#pragma unroll
            for (int n = 0; n < 4; ++n)
                acc[m][n] = __builtin_amdgcn_mfma_f32_16x16x32_bf16(
                    a[m], b[n], acc[m][n], 0, 0, 0);
        __syncthreads();
        cur ^= 1;
    }
#pragma unroll
    for (int m = 0; m < 4; ++m) {
#pragma unroll
        for (int r = 0; r < 4; ++r) {
            const int row = m0 + wr + m * 16 + (lane >> 4) * 4 + r;
            const size_t rb = (size_t)row * N;
#pragma unroll
            for (int n = 0; n < 4; ++n) {
                float val = acc[m][n][r];
                if (RELU) val = fmaxf(val, 0.0f);
                C[rb + n0 + wcol + n * 16 + fr] = val;
            }
        }
    }
}

// ---------------------------------------------------------------------------
// Chain-only SRU scan: c_t = f*c + (1-f)*xt, f = sigmoid(fp + vf*c + bf).
// Reads Uchain (xt,fp packed per uint), writes c (fp32).  asm-pinned
// double-buffer prefetch; steady-state waits are vmcnt(32) so fresh stores
// never gate (FIFO: [consumed buf][stores][next buf]).  256 blk x 64 thr.
// ---------------------------------------------------------------------------
__global__ __launch_bounds__(64)
void scan_c(const uint* __restrict__ Uc, const float* __restrict__ v,
            const float* __restrict__ bb, float* __restrict__ cbuf)
{
    const int gidx = blockIdx.x * 64 + threadIdx.x;    // 0..16383
    const int dir = gidx >> 13;
    const int idx = gidx & 8191;
    const int j = idx & 511, b = idx >> 9;
    float vf = v[dir * 1024 + j], bf_ = bb[dir * 1024 + j];
    const int off = b * 1024 + dir * 512 + j;          // elem offset in row
    asm volatile("" : "+v"(vf), "+v"(bf_));
    asm volatile("s_waitcnt vmcnt(0)" ::: "memory");

#define TT(q_) (dir ? (511 - (q_)) : (q_))
    float c = 0.0f;
    uint A[16], B[16];

#define ISSUE(dst, s_)                                                         \
    asm volatile("global_load_dword %0, %1, off"                               \
                 : "=v"(dst)                                                   \
                 : "v"(Uc + ((size_t)TT(s_) * 16384 + off))                    \
                 : "memory")
#define FILLW(BUF, wn_)                                                        \
    {                                                                          \
        _Pragma("unroll")                                                      \
        for (int q_ = 0; q_ < 16; ++q_) ISSUE(BUF[q_], (wn_) * 16 + q_);       \
    }
#define WAITB(BUF, NSTR)                                                       \
    asm volatile("s_waitcnt vmcnt(" NSTR ")"                                   \
                 : "+v"(BUF[0]), "+v"(BUF[1]), "+v"(BUF[2]), "+v"(BUF[3]),     \
                   "+v"(BUF[4]), "+v"(BUF[5]), "+v"(BUF[6]), "+v"(BUF[7]),     \
                   "+v"(BUF[8]), "+v"(BUF[9]), "+v"(BUF[10]), "+v"(BUF[11]),   \
                   "+v"(BUF[12]), "+v"(BUF[13]), "+v"(BUF[14]), "+v"(BUF[15])  \
                 :: "memory")
#define STEPC(val, s_)                                                         \
    {                                                                          \
        float xt = b2f(val & 0xffffu);                                         \
        float fp = b2f(val >> 16);                                             \
        float f = sigmoidf_(fp + vf * c + bf_);                                \
        c = fmaf(f, c - xt, xt);                                               \
        asm volatile("global_store_dword %0, %1, off"                          \
                     :: "v"(cbuf + ((size_t)TT(s_) * 16384 + off)), "v"(c)     \
                     : "memory");                                              \
    }

    FILLW(A, 0); FILLW(B, 1);
    // pair 0 (peeled: A-wait must be vmcnt(16) — only 32 ops outstanding)
    WAITB(A, "16");
#pragma unroll
    for (int q = 0; q < 16; ++q) STEPC(A[q], q);
    FILLW(A, 2);
    WAITB(B, "32");
#pragma unroll
    for (int q = 0; q < 16; ++q) STEPC(B[q], 16 + q);
    FILLW(B, 3);
    // pairs 1..14 (steady state: all waits vmcnt(32), never gated by stores)
    for (int p = 1; p < 15; ++p) {
        const int s0 = p * 32;
        WAITB(A, "32");
#pragma unroll
        for (int q = 0; q < 16; ++q) STEPC(A[q], s0 + q);
        FILLW(A, 2 * p + 2);
        WAITB(B, "32");
#pragma unroll
        for (int q = 0; q < 16; ++q) STEPC(B[q], s0 + 16 + q);
        FILLW(B, 2 * p + 3);
    }
    // pair 15 (peeled tail: no refills; B-wait must be vmcnt(16))
    WAITB(A, "32");
#pragma unroll
    for (int q = 0; q < 16; ++q) STEPC(A[q], 480 + q);
    WAITB(B, "16");
#pragma unroll
    for (int q = 0; q < 16; ++q) STEPC(B[q], 496 + q);
#undef STEPC
#undef WAITB
#undef FILLW
#undef ISSUE
#undef TT
}

// ---------------------------------------------------------------------------
// Final small GEMM (8192,512)@(512,29) with (t,b)->(b,t) output scatter.
// ---------------------------------------------------------------------------
__global__ __launch_bounds__(256)
void cls_out(const float* __restrict__ h1, const float* __restrict__ W2,
             float* __restrict__ out)
{
    const int gidx = blockIdx.x * 256 + threadIdx.x;
    const int n = gidx & 31, m = gidx >> 5;
    if (n >= 29) return;
    const float4* hr = (const float4*)(h1 + (size_t)m * 512);
    float acc = 0.0f;
    for (int k4 = 0; k4 < 128; ++k4) {
        float4 hv = hr[k4];
        const float* wp = W2 + (size_t)(k4 * 4) * 29 + n;
        acc = fmaf(hv.x, wp[0],  acc);
        acc = fmaf(hv.y, wp[29], acc);
        acc = fmaf(hv.z, wp[58], acc);
        acc = fmaf(hv.w, wp[87], acc);
    }
    const int t = m >> 4, b = m & 15;
    out[((size_t)b * 512 + t) * 29 + n] = acc;
}

// ---------------------------------------------------------------------------
// Host orchestration.  Workspace (floats):
//  conv: Xhi[0) Thi[8.69M)  convw@34742016  xrow@34865152  xn_bf@43253760
//  post: Uchain(ushort)@ws[0), Uout@+16.7M ushorts (= ws+8388608 floats)
//        cbuf/xch fp32 @16777216 ; proj_bt@25165824 ; sru_bt@26214400 ;
//        w1t@34603008 ; h1@0 (after last scan).
// ---------------------------------------------------------------------------
extern "C" void kernel_launch(void* const* d_in, const int* in_sizes, int n_in,
                              void* d_out, int out_size, void* d_ws, size_t ws_size,
                              hipStream_t stream)
{
    (void)in_sizes; (void)n_in; (void)out_size; (void)ws_size;
    const float* x      = (const float*)d_in[0];
    const float* cnn_w  = (const float*)d_in[1];
    const float* cnn_b  = (const float*)d_in[2];
    const float* c1w    = (const float*)d_in[3];
    const float* c1b    = (const float*)d_in[4];
    const float* bn1g   = (const float*)d_in[5];
    const float* bn1b   = (const float*)d_in[6];
    const float* bn1m   = (const float*)d_in[7];
    const float* bn1v   = (const float*)d_in[8];
    const float* c2w    = (const float*)d_in[9];
    const float* c2b    = (const float*)d_in[10];
    const float* bn2g   = (const float*)d_in[11];
    const float* bn2b   = (const float*)d_in[12];
    const float* bn2m   = (const float*)d_in[13];
    const float* bn2v   = (const float*)d_in[14];
    const float* projW  = (const float*)d_in[15];
    const float* sruW   = (const float*)d_in[16];
    const float* sruV   = (const float*)d_in[17];
    const float* sruB   = (const float*)d_in[18];
    const float* sruLNg = (const float*)d_in[19];
    const float* sruLNb = (const float*)d_in[20];
    const float* clsLNg = (const float*)d_in[21];
    const float* clsLNb = (const float*)d_in[22];
    const float* W1     = (const float*)d_in[23];
    const float* W2     = (const float*)d_in[24];
    float* out = (float*)d_out;
    float* ws  = (float*)d_ws;

    ushort* Xhi = (ushort*)ws;
    ushort* Thi = Xhi + PADN;
    ushort* convw_hi = (ushort*)(ws + 34742016);
    ushort* convw_lo = convw_hi + 55296;
    ushort* xrow_bf  = (ushort*)(ws + 34865152);   // [8192][2048]
    ushort* xn_bf    = (ushort*)(ws + 43253760);   // [8192][1024]
    ushort* Uchain   = (ushort*)ws;                // [8192][2048]
    ushort* Uout     = Uchain + 16777216;          // [8192][2048]
    float*  cbuf     = ws + 16777216;              // [8192][1024] fp32 (=xch)
    ushort* proj_bt  = (ushort*)(ws + 25165824);   // [1024][2048]
    ushort* sru_bt   = (ushort*)(ws + 26214400);   // 8 x [2048][1024]
    ushort* w1t      = (ushort*)(ws + 34603008);   // [512][1024]
    float*  h1       = ws;                         // [8192][512] fp32

    dim3 blk(256);

    // --- conv phase ---
    ring_zero<<<1160, blk, 0, stream>>>(Xhi, Thi);
    conv_wprep<<<6, blk, 0, stream>>>(c1w, c2w, convw_hi, convw_lo);
    conv_stem_p<<<dim3(8, 16, 16), blk, 0, stream>>>(x, cnn_w, cnn_b, Xhi);
    for (int i = 0; i < 3; ++i) {
        const int l1 = 2 * i, l2 = 2 * i + 1;
        conv_mfma<0><<<dim3(4, 16, 16), blk, 0, stream>>>(
            Xhi, convw_hi + l1 * 9216, convw_lo + l1 * 9216,
            bn1g + i * 32, bn1b + i * 32, bn1m + i * 32, bn1v + i * 32,
            c1b + i * 32, nullptr, Thi);
        conv_mfma<1><<<dim3(4, 16, 16), blk, 0, stream>>>(
            Thi, convw_hi + l2 * 9216, convw_lo + l2 * 9216,
            bn2g + i * 32, bn2b + i * 32, bn2m + i * 32, bn2v + i * 32,
            c2b + i * 32, Xhi, Xhi);
    }

    // --- GEMM weight conversion (SRU batched via z) ---
    wconv_t<<<dim3(32, 16, 1), blk, 0, stream>>>(projW, proj_bt, 2048, 1024, 0, 0, 0);
    wconv_t<<<dim3(16, 32, 8), blk, 0, stream>>>(sruW, sru_bt, 1024, 2048, 1,
                                                 2097152, 2097152);
    wconv_t<<<dim3(16, 8, 1), blk, 0, stream>>>(W1, w1t, 1024, 512, 0, 0, 0);

    // --- gather to bf16 rows ---
    gather_pad<<<dim3(32, 16), blk, 0, stream>>>(Xhi, xrow_bf);

    // --- proj GEMM: (8192,2048)@(2048,1024) -> cbuf(=xch) fp32 ---
    gemm_bf16<0><<<dim3(8, 64), blk, 0, stream>>>(
        xrow_bf, proj_bt, cbuf, 8192, 1024, 2048);

    // --- SRU layers: LN/lnh -> gemm256(split U) -> chain scan ---
    for (int l = 0; l < 4; ++l) {
        if (l == 0)
            layernorm1024_bf<<<8192, blk, 0, stream>>>(
                cbuf, sruLNg, sruLNb, xn_bf);
        else
            lnh<<<8192, blk, 0, stream>>>(
                cbuf, Uout, sruV + (l - 1) * 2048, sruB + (l - 1) * 2048,
                sruLNg + l * 1024, sruLNb + l * 1024, xn_bf);
        gemm256_bf16<<<dim3(16, 32), dim3(512), 0, stream>>>(
            xn_bf, sru_bt + (size_t)l * 4194304, Uchain, Uout, 8192, 4096, 1024);
        scan_c<<<256, dim3(64), 0, stream>>>(
            (const uint*)Uchain, sruV + l * 2048, sruB + l * 2048, cbuf);
    }

    // --- classifier (h of layer 3 + cls LN fused) ---
    lnh<<<8192, blk, 0, stream>>>(
        cbuf, Uout, sruV + 3 * 2048, sruB + 3 * 2048, clsLNg, clsLNb, xn_bf);
    gemm_bf16<1><<<dim3(4, 64), blk, 0, stream>>>(
        xn_bf, w1t, h1, 8192, 512, 1024);
    cls_out<<<1024, blk, 0, stream>>>(h1, W2, out);
}

// Round 13
// 795.660 us; speedup vs baseline: 1.2007x; 1.0219x over previous
//
#include <hip/hip_runtime.h>
#include <cstddef>

#define DEVFN __device__ __forceinline__

typedef __attribute__((ext_vector_type(8))) short short8;          // 8 bf16
typedef __attribute__((ext_vector_type(8))) unsigned short ushort8;
typedef __attribute__((ext_vector_type(4))) float f32x4;           // MFMA acc

DEVFN float sigmoidf_(float x) { return 1.0f / (1.0f + __expf(-x)); }
DEVFN float tanh_fast(float x) {
    float e = __expf(2.0f * x);
    return 1.0f - 2.0f / (e + 1.0f);
}
DEVFN unsigned short f2bf(float f) {            // round-to-nearest-even
    unsigned int u = __float_as_uint(f);
    return (unsigned short)((u + 0x7FFFu + ((u >> 16) & 1u)) >> 16);
}
DEVFN float b2f(unsigned int bits) { return __uint_as_float(bits << 16); }

DEVFN void gload_lds16(const ushort* g, ushort* l) {
    __builtin_amdgcn_global_load_lds(
        (const __attribute__((address_space(1))) unsigned int*)g,
        (__attribute__((address_space(3))) unsigned int*)l, 16, 0, 0);
}

// Padded NHWC geometry: [16 b][66 hs][514 ws][32 c], hs = h+1, ws = w+1.
#define PADN 17371008u

// ---------------------------------------------------------------------------
// Zero the padding ring of the 2 padded NHWC tensors.
// ---------------------------------------------------------------------------
__global__ __launch_bounds__(256)
void ring_zero(ushort* A, ushort* B)
{
    int idx = blockIdx.x * 256 + threadIdx.x;
    if (idx >= 296960) return;
    size_t uoff;
    if (idx < 263168) {                       // rows hs in {0,65}
        int b = idx / 16448, r = idx % 16448;
        int hs = (r < 8224) ? 0 : 65;
        int o = (r < 8224) ? r : r - 8224;
        uoff = (((size_t)(b * 66 + hs) * 514) * 32 + (size_t)o * 2) >> 1;
    } else {                                  // cols ws in {0,513}
        int j = idx - 263168;
        int b = j / 2112, r = j % 2112;
        int hs = r >> 5, e = r & 31;
        int wsp = (e < 16) ? 0 : 513;
        int c2 = e & 15;
        uoff = (((size_t)(b * 66 + hs) * 514 + wsp) * 32 + (size_t)c2 * 2) >> 1;
    }
    ((uint*)A)[uoff] = 0; ((uint*)B)[uoff] = 0;
}

// ---------------------------------------------------------------------------
// Conv-weight prep: [co][ci][3][3] fp32 -> [lay][q][co][ci] bf16 hi/lo.
// ---------------------------------------------------------------------------
__global__ __launch_bounds__(256)
void conv_wprep(const float* __restrict__ c1w, const float* __restrict__ c2w,
                ushort* __restrict__ whi, ushort* __restrict__ wlo)
{
    const int lay = blockIdx.x;               // 0..5
    const int i = lay >> 1;
    const float* src = (lay & 1) ? (c2w + i * 9216) : (c1w + i * 9216);
    for (int e = threadIdx.x; e < 9216; e += 256) {
        int co = e / 288, rem = e % 288, ci = rem / 9, q = rem % 9;
        float v = src[e];
        unsigned short hi = f2bf(v);
        unsigned short lo = f2bf(v - b2f(hi));
        int dst = ((lay * 9 + q) * 32 + co) * 32 + ci;
        whi[dst] = hi; wlo[dst] = lo;
    }
}

// ---------------------------------------------------------------------------
// Conv stem -> padded NHWC bf16. x (16,1,128,1024), stride 2, pad 1.
// ---------------------------------------------------------------------------
__global__ __launch_bounds__(256)
void conv_stem_p(const float* __restrict__ x, const float* __restrict__ w,
                 const float* __restrict__ cb, ushort* __restrict__ Xhi)
{
    const int b = blockIdx.z;
    const int h = blockIdx.y * 4 + (threadIdx.x >> 6);
    const int wc = blockIdx.x * 64 + (threadIdx.x & 63);
    float iv[9];
#pragma unroll
    for (int kh = 0; kh < 3; ++kh)
#pragma unroll
        for (int kw = 0; kw < 3; ++kw) {
            int ih = 2 * h - 1 + kh, iw = 2 * wc - 1 + kw;
            iv[kh * 3 + kw] = (ih >= 0 && ih < 128 && iw >= 0 && iw < 1024)
                ? x[(size_t)b * 131072 + (size_t)ih * 1024 + iw] : 0.0f;
        }
    unsigned short hi[32];
#pragma unroll
    for (int co = 0; co < 32; ++co) {
        const float* wp = w + co * 9;
        float a = cb[co];
#pragma unroll
        for (int q = 0; q < 9; ++q) a = fmaf(iv[q], wp[q], a);
        hi[co] = f2bf(a);
    }
    const size_t o = ((size_t)(b * 66 + h + 1) * 514 + wc + 1) * 32;
#pragma unroll
    for (int v = 0; v < 4; ++v) {
        ushort8 uh;
#pragma unroll
        for (int e = 0; e < 8; ++e) uh[e] = hi[v * 8 + e];
        *(ushort8*)(Xhi + o + v * 8) = uh;
    }
}

// ---------------------------------------------------------------------------
// MFMA implicit-GEMM conv 3x3 (32->32) + BN (+res) + ReLU.
// v4: h-block = 8 rows (halo factor 1.25x) + chunked XCD swizzle (T1):
// physical bid -> lid = (bid%8)*64 + bid/8, lid = [b(16)][wt(4)][hb(8)],
// so halo-sharing h-neighbors run on the same XCD's L2.
// ---------------------------------------------------------------------------
template <int RES>
__global__ __launch_bounds__(256)
void conv_mfma(const ushort* __restrict__ Phi,
               const ushort* __restrict__ gwhi, const ushort* __restrict__ gwlo,
               const float* __restrict__ g, const float* __restrict__ bbn,
               const float* __restrict__ mn, const float* __restrict__ vn,
               const float* __restrict__ cbv,
               const ushort* __restrict__ Rhi, ushort* __restrict__ Ohi)
{
    __shared__ __align__(16) ushort Wsh[9216], Wsl[9216];
    const int tid = threadIdx.x, lane = tid & 63, wv = tid >> 6;
    const int lid = (blockIdx.x & 7) * 64 + (blockIdx.x >> 3);   // 512 blocks
    const int hb = lid & 7, wt = (lid >> 3) & 3, b = lid >> 5;
    const int h0 = hb * 8, w0 = wt * 128;

    for (int i = tid; i < 1152; i += 256) {
        ((uint4*)Wsh)[i] = ((const uint4*)gwhi)[i];
        ((uint4*)Wsl)[i] = ((const uint4*)gwlo)[i];
    }
    __syncthreads();

    const int wr = wv * 32;
    const int fr = lane & 15, fk = (lane >> 4) * 8;
    const int lo0 = (wr + fr) * 32 + fk;
    const int lo1 = (wr + 16 + fr) * 32 + fk;

    float sc[2], sh[2];
#pragma unroll
    for (int n = 0; n < 2; ++n) {
        const int co = n * 16 + fr;
        sc[n] = g[co] * rsqrtf(vn[co] + 1e-5f);
        sh[n] = bbn[co] - mn[co] * sc[n] + cbv[co] * sc[n];
    }

    short8 A[3][2][3];
#define LOADROW(SL, PR)                                                        \
    {                                                                          \
        const size_t rb_ = ((size_t)(b * 66 + (PR)) * 514 + w0) * 32;          \
        _Pragma("unroll")                                                      \
        for (int kw_ = 0; kw_ < 3; ++kw_) {                                    \
            A[SL][0][kw_] = *(const short8*)(Phi + rb_ + kw_ * 32 + lo0);      \
            A[SL][1][kw_] = *(const short8*)(Phi + rb_ + kw_ * 32 + lo1);      \
        }                                                                      \
    }

    LOADROW(0, h0);
    LOADROW(1, h0 + 1);

#pragma unroll
    for (int hh = 0; hh < 8; ++hh) {
        LOADROW((hh + 2) % 3, h0 + hh + 2);
        f32x4 acc[2][2];
#pragma unroll
        for (int m = 0; m < 2; ++m)
#pragma unroll
            for (int n = 0; n < 2; ++n) acc[m][n] = (f32x4){0.f, 0.f, 0.f, 0.f};
#pragma unroll
        for (int kh = 0; kh < 3; ++kh) {
            const int sl = (hh + kh) % 3;
#pragma unroll
            for (int kw = 0; kw < 3; ++kw) {
                const int q = kh * 3 + kw;
                short8 ah0 = A[sl][0][kw];
                short8 ah1 = A[sl][1][kw];
                short8 bh0 = *(const short8*)&Wsh[q * 1024 + fr * 32 + fk];
                short8 bh1 = *(const short8*)&Wsh[q * 1024 + (16 + fr) * 32 + fk];
                short8 bl0 = *(const short8*)&Wsl[q * 1024 + fr * 32 + fk];
                short8 bl1 = *(const short8*)&Wsl[q * 1024 + (16 + fr) * 32 + fk];
                acc[0][0] = __builtin_amdgcn_mfma_f32_16x16x32_bf16(ah0, bh0, acc[0][0], 0, 0, 0);
                acc[0][1] = __builtin_amdgcn_mfma_f32_16x16x32_bf16(ah0, bh1, acc[0][1], 0, 0, 0);
                acc[1][0] = __builtin_amdgcn_mfma_f32_16x16x32_bf16(ah1, bh0, acc[1][0], 0, 0, 0);
                acc[1][1] = __builtin_amdgcn_mfma_f32_16x16x32_bf16(ah1, bh1, acc[1][1], 0, 0, 0);
                acc[0][0] = __builtin_amdgcn_mfma_f32_16x16x32_bf16(ah0, bl0, acc[0][0], 0, 0, 0);
                acc[0][1] = __builtin_amdgcn_mfma_f32_16x16x32_bf16(ah0, bl1, acc[0][1], 0, 0, 0);
                acc[1][0] = __builtin_amdgcn_mfma_f32_16x16x32_bf16(ah1, bl0, acc[1][0], 0, 0, 0);
                acc[1][1] = __builtin_amdgcn_mfma_f32_16x16x32_bf16(ah1, bl1, acc[1][1], 0, 0, 0);
            }
        }
#pragma unroll
        for (int m = 0; m < 2; ++m)
#pragma unroll
            for (int r = 0; r < 4; ++r) {
                const int wl = wr + m * 16 + (lane >> 4) * 4 + r;
                const size_t oidx =
                    ((size_t)(b * 66 + h0 + hh + 1) * 514 + w0 + wl + 1) * 32;
#pragma unroll
                for (int n = 0; n < 2; ++n) {
                    const int co = n * 16 + fr;
                    float val = acc[m][n][r] * sc[n] + sh[n];
                    if (RES) val += b2f(Rhi[oidx + co]);
                    val = fmaxf(val, 0.0f);
                    Ohi[oidx + co] = f2bf(val);
                }
            }
    }
#undef LOADROW
}

// ---------------------------------------------------------------------------
// Gather: padded NHWC -> xrow_bf[(w*16+b)][c*64+h]  (8192 x 2048 bf16)
// ---------------------------------------------------------------------------
__global__ __launch_bounds__(256)
void gather_pad(const ushort* __restrict__ Xhi, ushort* __restrict__ xrow)
{
    __shared__ ushort tile[64 * 16 * 32];        // [h][wl][c], 64 KB
    const int b = blockIdx.y, w0 = blockIdx.x * 16;
    for (int k = threadIdx.x; k < 4096; k += 256) {
        int h = k >> 6, rem = k & 63, wl = rem >> 2, c8 = (rem & 3) * 8;
        const ushort* src = Xhi + ((size_t)(b * 66 + h + 1) * 514 + w0 + 1 + wl) * 32 + c8;
        *(ushort8*)&tile[(h * 16 + wl) * 32 + c8] = *(const ushort8*)src;
    }
    __syncthreads();
    for (int k = threadIdx.x; k < 4096; k += 256) {
        int wl = k >> 8, rem = k & 255, c = rem >> 3, h8 = (rem & 7) * 8;
        ushort8 v;
#pragma unroll
        for (int e = 0; e < 8; ++e) v[e] = tile[((h8 + e) * 16 + wl) * 32 + c];
        *(ushort8*)&xrow[((size_t)(w0 + wl) * 16 + b) * 2048 + c * 64 + h8] = v;
    }
}

// ---------------------------------------------------------------------------
// Weight transpose+convert: W [K][N] fp32 -> Bt [N'][K] bf16.
// perm=1 (SRU): within N=2048, n = gate*512+j -> n' = j*4+gate.
// ---------------------------------------------------------------------------
__global__ __launch_bounds__(256)
void wconv_t(const float* __restrict__ W, ushort* __restrict__ Bt,
             int K, int N, int perm, size_t wstr, size_t btstr)
{
    __shared__ float tile[64][65];
    const float* Wp = W + (size_t)blockIdx.z * wstr;
    ushort* Btp = Bt + (size_t)blockIdx.z * btstr;
    const int k0 = blockIdx.x * 64;
    const int n0 = blockIdx.y * 64;
#pragma unroll
    for (int p = 0; p < 16; ++p) {
        int idx = p * 256 + threadIdx.x;
        int kl = idx >> 6, nl = idx & 63;
        tile[kl][nl] = Wp[(size_t)(k0 + kl) * N + n0 + nl];
    }
    __syncthreads();
#pragma unroll
    for (int p = 0; p < 16; ++p) {
        int idx = p * 256 + threadIdx.x;
        int nl = idx >> 6, kl = idx & 63;
        int n = n0 + nl;
        int row = perm ? ((n & 511) * 4 + (n >> 9)) : n;
        Btp[(size_t)row * K + k0 + kl] = f2bf(tile[kl][nl]);
    }
}

// ---------------------------------------------------------------------------
// LayerNorm over last dim (1024), rows = 8192, fp32 in -> bf16 out.
// ---------------------------------------------------------------------------
__global__ __launch_bounds__(256)
void layernorm1024_bf(const float* __restrict__ x, const float* __restrict__ g,
                      const float* __restrict__ b, ushort* __restrict__ y)
{
    const size_t row = blockIdx.x;
    const float4 v = ((const float4*)(x + row * 1024))[threadIdx.x];
    float s = v.x + v.y + v.z + v.w;
    float s2 = v.x * v.x + v.y * v.y + v.z * v.z + v.w * v.w;
#pragma unroll
    for (int off = 32; off; off >>= 1) {
        s += __shfl_down(s, off);
        s2 += __shfl_down(s2, off);
    }
    __shared__ float red[2][4];
    int wid = threadIdx.x >> 6, lane = threadIdx.x & 63;
    if (lane == 0) { red[0][wid] = s; red[1][wid] = s2; }
    __syncthreads();
    s = red[0][0] + red[0][1] + red[0][2] + red[0][3];
    s2 = red[1][0] + red[1][1] + red[1][2] + red[1][3];
    float mu = s * (1.0f / 1024.0f);
    float var = s2 * (1.0f / 1024.0f) - mu * mu;
    float rstd = rsqrtf(var + 1e-5f);
    float4 gv = ((const float4*)g)[threadIdx.x];
    float4 bv = ((const float4*)b)[threadIdx.x];
    ushort4 o;
    o.x = f2bf((v.x - mu) * rstd * gv.x + bv.x);
    o.y = f2bf((v.y - mu) * rstd * gv.y + bv.y);
    o.z = f2bf((v.z - mu) * rstd * gv.z + bv.z);
    o.w = f2bf((v.w - mu) * rstd * gv.w + bv.w);
    ((ushort4*)(y + row * 1024))[threadIdx.x] = o;
}

// ---------------------------------------------------------------------------
// Fused h-compute + LayerNorm (rows t*16+b).
// ---------------------------------------------------------------------------
__global__ __launch_bounds__(256)
void lnh(const float* __restrict__ cbuf, const ushort* __restrict__ Uo,
         const float* __restrict__ v, const float* __restrict__ bb,
         const float* __restrict__ g, const float* __restrict__ be,
         ushort* __restrict__ y)
{
    const int r = blockIdx.x, t = r >> 4;
    const int tid = threadIdx.x, dir = tid >> 7;
    const int jj = (tid * 4) & 511;
    float4 cc = *(const float4*)(cbuf + (size_t)r * 1024 + tid * 4);
    const int pr = dir ? (t == 511 ? -1 : r + 16) : (t == 0 ? -1 : r - 16);
    float4 cp = {0.f, 0.f, 0.f, 0.f};
    if (pr >= 0) cp = *(const float4*)(cbuf + (size_t)pr * 1024 + tid * 4);
    ushort8 u = *(const ushort8*)(Uo + (size_t)r * 2048 + dir * 1024 + jj * 2);
    float4 vr = *(const float4*)(v + dir * 1024 + 512 + jj);
    float4 br = *(const float4*)(bb + dir * 1024 + 512 + jj);
    float h[4];
    const float cpe[4] = {cp.x, cp.y, cp.z, cp.w};
    const float cce[4] = {cc.x, cc.y, cc.z, cc.w};
    const float vre[4] = {vr.x, vr.y, vr.z, vr.w};
    const float bre[4] = {br.x, br.y, br.z, br.w};
#pragma unroll
    for (int e = 0; e < 4; ++e) {
        float rp = b2f(u[2 * e]);
        float xp = b2f(u[2 * e + 1]);
        float rg = sigmoidf_(rp + vre[e] * cpe[e] + bre[e]);
        h[e] = fmaf(rg, tanh_fast(cce[e]) - xp, xp);
    }
    float s = h[0] + h[1] + h[2] + h[3];
    float s2 = h[0] * h[0] + h[1] * h[1] + h[2] * h[2] + h[3] * h[3];
#pragma unroll
    for (int off = 32; off; off >>= 1) {
        s += __shfl_down(s, off);
        s2 += __shfl_down(s2, off);
    }
    __shared__ float red[2][4];
    int wid = tid >> 6, lane = tid & 63;
    if (lane == 0) { red[0][wid] = s; red[1][wid] = s2; }
    __syncthreads();
    s = red[0][0] + red[0][1] + red[0][2] + red[0][3];
    s2 = red[1][0] + red[1][1] + red[1][2] + red[1][3];
    float mu = s * (1.0f / 1024.0f);
    float var = s2 * (1.0f / 1024.0f) - mu * mu;
    float rstd = rsqrtf(var + 1e-5f);
    float4 gv = ((const float4*)g)[tid];
    float4 bv = ((const float4*)be)[tid];
    ushort4 o;
    o.x = f2bf((h[0] - mu) * rstd * gv.x + bv.x);
    o.y = f2bf((h[1] - mu) * rstd * gv.y + bv.y);
    o.z = f2bf((h[2] - mu) * rstd * gv.z + bv.z);
    o.w = f2bf((h[3] - mu) * rstd * gv.w + bv.w);
    ((ushort4*)(y + (size_t)r * 1024))[tid] = o;
}

// ---------------------------------------------------------------------------
// 256x256 8-phase bf16 GEMM, SRU variant.  v2: 3-bit K-loop swizzle
// (row&7 — Guideline-4 pattern) + swizzled epilogue C-tile.
// Epilogue splits gate-interleaved output into Uchain (xt,fp) / Uout (rp,xp).
// ---------------------------------------------------------------------------
__global__ __launch_bounds__(512, 2)
void gemm256_bf16(const ushort* __restrict__ A, const ushort* __restrict__ Bt,
                  ushort* __restrict__ Uc, ushort* __restrict__ Uo,
                  int M, int N, int K)
{
    __shared__ __align__(16) ushort LDS[65536];   // A:[2][16384], B:+32768
    const int tid = threadIdx.x;
    const int lane = tid & 63, w = tid >> 6;
    const int wm = w >> 2, wn = w & 3;            // 2 x 4 wave grid
    const int m0 = blockIdx.y * 256, n0 = blockIdx.x * 256;
    const int fr = lane & 15, fk = (lane >> 4) * 8;
    const int NT = K >> 6;

    const int sprow = tid >> 3;                   // row within 64-row quarter
    const int scb0 = (tid & 7) * 16;              // byte col within 128B row
    const int wq = w * 512;                       // wave base (elements) in quarter

    f32x4 acc[8][4];
#pragma unroll
    for (int i = 0; i < 8; ++i)
#pragma unroll
        for (int j = 0; j < 4; ++j) acc[i][j] = (f32x4){0.f, 0.f, 0.f, 0.f};

    auto stage = [&](int dbuf, int isB, int qi, int kt) {
        const int prow = qi * 64 + sprow;
        const int sc = scb0 ^ ((prow & 7) << 4);          // inverse 3-bit swz
        const ushort* g = (isB ? (Bt + (size_t)(n0 + prow) * K)
                               : (A + (size_t)(m0 + prow) * K))
                          + (kt << 6) + (sc >> 1);
        gload_lds16(g, LDS + (isB ? 32768 : 0) + dbuf * 16384 + qi * 4096 + wq);
    };
    auto rdA = [&](int dbuf, int mi8, int ks) -> short8 {
        const int row = wm * 128 + mi8 * 16 + fr;
        int e = (row * 64 + ks * 32 + fk) ^ ((row & 7) << 3);
        return *(const short8*)&LDS[dbuf * 16384 + e];
    };
    auto rdB = [&](int dbuf, int ni, int ks) -> short8 {
        const int row = wn * 64 + ni * 16 + fr;
        int e = (row * 64 + ks * 32 + fk) ^ ((row & 7) << 3);
        return *(const short8*)&LDS[32768 + dbuf * 16384 + e];
    };

#pragma unroll
    for (int qi = 0; qi < 4; ++qi) stage(0, 0, qi, 0);
#pragma unroll
    for (int qi = 0; qi < 4; ++qi) stage(0, 1, qi, 0);

    for (int kt = 0; kt < NT; ++kt) {
        const int cur = kt & 1, nxt = cur ^ 1;
        const bool more = (kt + 1 < NT);
        short8 bfr[4], afr[4];

        // ---- phase 0
        if (more) {
            stage(nxt, 0, 0, kt + 1); stage(nxt, 0, 1, kt + 1);
            asm volatile("s_waitcnt vmcnt(2)" ::: "memory");
        } else {
            asm volatile("s_waitcnt vmcnt(0)" ::: "memory");
        }
        __builtin_amdgcn_s_barrier();
#pragma unroll
        for (int ni = 0; ni < 4; ++ni) bfr[ni] = rdB(cur, ni, 0);
#pragma unroll
        for (int mi = 0; mi < 4; ++mi) afr[mi] = rdA(cur, mi, 0);
        __builtin_amdgcn_s_setprio(1);
#pragma unroll
        for (int mi = 0; mi < 4; ++mi)
#pragma unroll
            for (int ni = 0; ni < 4; ++ni)
                acc[mi][ni] = __builtin_amdgcn_mfma_f32_16x16x32_bf16(
                    afr[mi], bfr[ni], acc[mi][ni], 0, 0, 0);
        __builtin_amdgcn_s_setprio(0);

        // ---- phase 1
        if (more) { stage(nxt, 0, 2, kt + 1); stage(nxt, 0, 3, kt + 1); }
#pragma unroll
        for (int mi = 0; mi < 4; ++mi) afr[mi] = rdA(cur, 4 + mi, 0);
        __builtin_amdgcn_s_setprio(1);
#pragma unroll
        for (int mi = 0; mi < 4; ++mi)
#pragma unroll
            for (int ni = 0; ni < 4; ++ni)
                acc[4 + mi][ni] = __builtin_amdgcn_mfma_f32_16x16x32_bf16(
                    afr[mi], bfr[ni], acc[4 + mi][ni], 0, 0, 0);
        __builtin_amdgcn_s_setprio(0);

        // ---- phase 2
        if (more) { stage(nxt, 1, 0, kt + 1); stage(nxt, 1, 1, kt + 1); }
#pragma unroll
        for (int ni = 0; ni < 4; ++ni) bfr[ni] = rdB(cur, ni, 1);
#pragma unroll
        for (int mi = 0; mi < 4; ++mi) afr[mi] = rdA(cur, mi, 1);
        __builtin_amdgcn_s_setprio(1);
#pragma unroll
        for (int mi = 0; mi < 4; ++mi)
#pragma unroll
            for (int ni = 0; ni < 4; ++ni)
                acc[mi][ni] = __builtin_amdgcn_mfma_f32_16x16x32_bf16(
                    afr[mi], bfr[ni], acc[mi][ni], 0, 0, 0);
        __builtin_amdgcn_s_setprio(0);

        // ---- phase 3
        if (more) { stage(nxt, 1, 2, kt + 1); stage(nxt, 1, 3, kt + 1); }
#pragma unroll
        for (int mi = 0; mi < 4; ++mi) afr[mi] = rdA(cur, 4 + mi, 1);
        __builtin_amdgcn_s_setprio(1);
#pragma unroll
        for (int mi = 0; mi < 4; ++mi)
#pragma unroll
            for (int ni = 0; ni < 4; ++ni)
                acc[4 + mi][ni] = __builtin_amdgcn_mfma_f32_16x16x32_bf16(
                    afr[mi], bfr[ni], acc[4 + mi][ni], 0, 0, 0);
        __builtin_amdgcn_s_setprio(0);

        __builtin_amdgcn_s_barrier();     // all waves done reading buf cur
    }

    // epilogue: bf16 C-tile via LDS (swizzled: col ^= ((row>>2)&3)<<4)
#pragma unroll
    for (int mi8 = 0; mi8 < 8; ++mi8)
#pragma unroll
        for (int r = 0; r < 4; ++r) {
            const int row = wm * 128 + mi8 * 16 + (lane >> 4) * 4 + r;
            const int sw = ((row >> 2) & 3) << 4;
#pragma unroll
            for (int ni = 0; ni < 4; ++ni)
                LDS[row * 256 + ((wn * 64 + ni * 16 + fr) ^ sw)] =
                    f2bf(acc[mi8][ni][r]);
        }
    __builtin_amdgcn_s_barrier();
    const int frow = tid >> 5, fcb = (tid & 31) * 8;
    const int g0 = n0 + fcb;
    const int dirq = g0 >> 11, j0 = (g0 & 2047) >> 2;
    const size_t cbase = (size_t)dirq * 1024 + j0 * 2;
#pragma unroll
    for (int it = 0; it < 16; ++it) {
        const int row = it * 16 + frow;
        const int fcb2 = fcb ^ (((row >> 2) & 3) << 4);
        ushort8 vv = *(const ushort8*)&LDS[row * 256 + fcb2];
        uint2 ch, uo;
        ch.x = (uint)vv[0] | ((uint)vv[1] << 16);
        ch.y = (uint)vv[4] | ((uint)vv[5] << 16);
        uo.x = (uint)vv[2] | ((uint)vv[3] << 16);
        uo.y = (uint)vv[6] | ((uint)vv[7] << 16);
        const size_t rb = (size_t)(m0 + row) * 2048 + cbase;
        *(uint2*)&Uc[rb] = ch;
        *(uint2*)&Uo[rb] = uo;
    }
}

// ---------------------------------------------------------------------------
// bf16 MFMA GEMM (128² 2-phase) — used for proj and classifier (fp32 out).
// ---------------------------------------------------------------------------
template <int RELU>
__global__ __launch_bounds__(256)
void gemm_bf16(const ushort* __restrict__ A, const ushort* __restrict__ Bt,
               float* __restrict__ C, int M, int N, int K)
{
    __shared__ __align__(16) ushort Sh[4][4096];   // [0..1]=A dbuf, [2..3]=B dbuf
    const int tid = threadIdx.x;
    const int lane = tid & 63, w = tid >> 6;
    const int m0 = blockIdx.y * 128, n0 = blockIdx.x * 128;
    const int srow = lane >> 2;
    const int skel = (lane & 3) * 8;
    const int wr = (w >> 1) * 64, wcol = (w & 1) * 64;
    const int fr = lane & 15, fk = (lane >> 4) * 8;

    f32x4 acc[4][4];
#pragma unroll
    for (int m = 0; m < 4; ++m)
#pragma unroll
        for (int n = 0; n < 4; ++n) acc[m][n] = (f32x4){0.f, 0.f, 0.f, 0.f};

#pragma unroll
    for (int q = 0; q < 2; ++q) {
        const int ch = w * 2 + q;
        gload_lds16(A + (size_t)(m0 + ch * 16 + srow) * K + skel, &Sh[0][ch * 512]);
        gload_lds16(Bt + (size_t)(n0 + ch * 16 + srow) * K + skel, &Sh[2][ch * 512]);
    }
    __syncthreads();

    int cur = 0;
    for (int k0 = 0; k0 < K; k0 += 32) {
        if (k0 + 32 < K) {
#pragma unroll
            for (int q = 0; q < 2; ++q) {
                const int ch = w * 2 + q;
                gload_lds16(A + (size_t)(m0 + ch * 16 + srow) * K + k0 + 32 + skel,
                            &Sh[cur ^ 1][ch * 512]);
                gload_lds16(Bt + (size_t)(n0 + ch * 16 + srow) * K + k0 + 32 + skel,
                            &Sh[2 + (cur ^ 1)][ch * 512]);
            }
        }
        short8 a[4], b[4];
#pragma unroll
        for (int m = 0; m < 4; ++m)
            a[m] = *(const short8*)&Sh[cur][(wr + m * 16 + fr) * 32 + fk];
#pragma unroll
        for (int n = 0; n < 4; ++n)
            b[n] = *(const short8*)&Sh[2 + cur][(wcol + n * 16 + fr) * 32 + fk];
#pragma unroll
        for (int m = 0; m < 4; ++m)
#pragma unroll
            for (int n = 0; n < 4; ++n)
                acc[m][n] = __builtin_amdgcn_mfma_f32_16x16x32_bf16(
                    a[m], b[n], acc[m][n], 0, 0, 0);
        __syncthreads();
        cur ^= 1;
    }
#pragma unroll
    for (int m = 0; m < 4; ++m) {
#pragma unroll
        for (int r = 0; r < 4; ++r) {
            const int row = m0 + wr + m * 16 + (lane >> 4) * 4 + r;
            const size_t rb = (size_t)row * N;
#pragma unroll
            for (int n = 0; n < 4; ++n) {
                float val = acc[m][n][r];
                if (RELU) val = fmaxf(val, 0.0f);
                C[rb + n0 + wcol + n * 16 + fr] = val;
            }
        }
    }
}

// ---------------------------------------------------------------------------
// Chain-only SRU scan (asm-pinned double-buffer prefetch, vmcnt(32) steady).
// ---------------------------------------------------------------------------
__global__ __launch_bounds__(64)
void scan_c(const uint* __restrict__ Uc, const float* __restrict__ v,
            const float* __restrict__ bb, float* __restrict__ cbuf)
{
    const int gidx = blockIdx.x * 64 + threadIdx.x;    // 0..16383
    const int dir = gidx >> 13;
    const int idx = gidx & 8191;
    const int j = idx & 511, b = idx >> 9;
    float vf = v[dir * 1024 + j], bf_ = bb[dir * 1024 + j];
    const int off = b * 1024 + dir * 512 + j;          // elem offset in row
    asm volatile("" : "+v"(vf), "+v"(bf_));
    asm volatile("s_waitcnt vmcnt(0)" ::: "memory");

#define TT(q_) (dir ? (511 - (q_)) : (q_))
    float c = 0.0f;
    uint A[16], B[16];

#define ISSUE(dst, s_)                                                         \
    asm volatile("global_load_dword %0, %1, off"                               \
                 : "=v"(dst)                                                   \
                 : "v"(Uc + ((size_t)TT(s_) * 16384 + off))                    \
                 : "memory")
#define FILLW(BUF, wn_)                                                        \
    {                                                                          \
        _Pragma("unroll")                                                      \
        for (int q_ = 0; q_ < 16; ++q_) ISSUE(BUF[q_], (wn_) * 16 + q_);       \
    }
#define WAITB(BUF, NSTR)                                                       \
    asm volatile("s_waitcnt vmcnt(" NSTR ")"                                   \
                 : "+v"(BUF[0]), "+v"(BUF[1]), "+v"(BUF[2]), "+v"(BUF[3]),     \
                   "+v"(BUF[4]), "+v"(BUF[5]), "+v"(BUF[6]), "+v"(BUF[7]),     \
                   "+v"(BUF[8]), "+v"(BUF[9]), "+v"(BUF[10]), "+v"(BUF[11]),   \
                   "+v"(BUF[12]), "+v"(BUF[13]), "+v"(BUF[14]), "+v"(BUF[15])  \
                 :: "memory")
#define STEPC(val, s_)                                                         \
    {                                                                          \
        float xt = b2f(val & 0xffffu);                                         \
        float fp = b2f(val >> 16);                                             \
        float f = sigmoidf_(fp + vf * c + bf_);                                \
        c = fmaf(f, c - xt, xt);                                               \
        asm volatile("global_store_dword %0, %1, off"                          \
                     :: "v"(cbuf + ((size_t)TT(s_) * 16384 + off)), "v"(c)     \
                     : "memory");                                              \
    }

    FILLW(A, 0); FILLW(B, 1);
    WAITB(A, "16");
#pragma unroll
    for (int q = 0; q < 16; ++q) STEPC(A[q], q);
    FILLW(A, 2);
    WAITB(B, "32");
#pragma unroll
    for (int q = 0; q < 16; ++q) STEPC(B[q], 16 + q);
    FILLW(B, 3);
    for (int p = 1; p < 15; ++p) {
        const int s0 = p * 32;
        WAITB(A, "32");
#pragma unroll
        for (int q = 0; q < 16; ++q) STEPC(A[q], s0 + q);
        FILLW(A, 2 * p + 2);
        WAITB(B, "32");
#pragma unroll
        for (int q = 0; q < 16; ++q) STEPC(B[q], s0 + 16 + q);
        FILLW(B, 2 * p + 3);
    }
    WAITB(A, "32");
#pragma unroll
    for (int q = 0; q < 16; ++q) STEPC(A[q], 480 + q);
    WAITB(B, "16");
#pragma unroll
    for (int q = 0; q < 16; ++q) STEPC(B[q], 496 + q);
#undef STEPC
#undef WAITB
#undef FILLW
#undef ISSUE
#undef TT
}

// ---------------------------------------------------------------------------
// Final small GEMM (8192,512)@(512,29) with (t,b)->(b,t) output scatter.
// ---------------------------------------------------------------------------
__global__ __launch_bounds__(256)
void cls_out(const float* __restrict__ h1, const float* __restrict__ W2,
             float* __restrict__ out)
{
    const int gidx = blockIdx.x * 256 + threadIdx.x;
    const int n = gidx & 31, m = gidx >> 5;
    if (n >= 29) return;
    const float4* hr = (const float4*)(h1 + (size_t)m * 512);
    float acc = 0.0f;
    for (int k4 = 0; k4 < 128; ++k4) {
        float4 hv = hr[k4];
        const float* wp = W2 + (size_t)(k4 * 4) * 29 + n;
        acc = fmaf(hv.x, wp[0],  acc);
        acc = fmaf(hv.y, wp[29], acc);
        acc = fmaf(hv.z, wp[58], acc);
        acc = fmaf(hv.w, wp[87], acc);
    }
    const int t = m >> 4, b = m & 15;
    out[((size_t)b * 512 + t) * 29 + n] = acc;
}

// ---------------------------------------------------------------------------
// Host orchestration.  Workspace layout identical to round 12.
// ---------------------------------------------------------------------------
extern "C" void kernel_launch(void* const* d_in, const int* in_sizes, int n_in,
                              void* d_out, int out_size, void* d_ws, size_t ws_size,
                              hipStream_t stream)
{
    (void)in_sizes; (void)n_in; (void)out_size; (void)ws_size;
    const float* x      = (const float*)d_in[0];
    const float* cnn_w  = (const float*)d_in[1];
    const float* cnn_b  = (const float*)d_in[2];
    const float* c1w    = (const float*)d_in[3];
    const float* c1b    = (const float*)d_in[4];
    const float* bn1g   = (const float*)d_in[5];
    const float* bn1b   = (const float*)d_in[6];
    const float* bn1m   = (const float*)d_in[7];
    const float* bn1v   = (const float*)d_in[8];
    const float* c2w    = (const float*)d_in[9];
    const float* c2b    = (const float*)d_in[10];
    const float* bn2g   = (const float*)d_in[11];
    const float* bn2b   = (const float*)d_in[12];
    const float* bn2m   = (const float*)d_in[13];
    const float* bn2v   = (const float*)d_in[14];
    const float* projW  = (const float*)d_in[15];
    const float* sruW   = (const float*)d_in[16];
    const float* sruV   = (const float*)d_in[17];
    const float* sruB   = (const float*)d_in[18];
    const float* sruLNg = (const float*)d_in[19];
    const float* sruLNb = (const float*)d_in[20];
    const float* clsLNg = (const float*)d_in[21];
    const float* clsLNb = (const float*)d_in[22];
    const float* W1     = (const float*)d_in[23];
    const float* W2     = (const float*)d_in[24];
    float* out = (float*)d_out;
    float* ws  = (float*)d_ws;

    ushort* Xhi = (ushort*)ws;
    ushort* Thi = Xhi + PADN;
    ushort* convw_hi = (ushort*)(ws + 34742016);
    ushort* convw_lo = convw_hi + 55296;
    ushort* xrow_bf  = (ushort*)(ws + 34865152);   // [8192][2048]
    ushort* xn_bf    = (ushort*)(ws + 43253760);   // [8192][1024]
    ushort* Uchain   = (ushort*)ws;                // [8192][2048]
    ushort* Uout     = Uchain + 16777216;          // [8192][2048]
    float*  cbuf     = ws + 16777216;              // [8192][1024] fp32
    ushort* proj_bt  = (ushort*)(ws + 25165824);   // [1024][2048]
    ushort* sru_bt   = (ushort*)(ws + 26214400);   // 8 x [2048][1024]
    ushort* w1t      = (ushort*)(ws + 34603008);   // [512][1024]
    float*  h1       = ws;                         // [8192][512] fp32

    dim3 blk(256);

    // --- conv phase ---
    ring_zero<<<1160, blk, 0, stream>>>(Xhi, Thi);
    conv_wprep<<<6, blk, 0, stream>>>(c1w, c2w, convw_hi, convw_lo);
    conv_stem_p<<<dim3(8, 16, 16), blk, 0, stream>>>(x, cnn_w, cnn_b, Xhi);
    for (int i = 0; i < 3; ++i) {
        const int l1 = 2 * i, l2 = 2 * i + 1;
        conv_mfma<0><<<512, blk, 0, stream>>>(
            Xhi, convw_hi + l1 * 9216, convw_lo + l1 * 9216,
            bn1g + i * 32, bn1b + i * 32, bn1m + i * 32, bn1v + i * 32,
            c1b + i * 32, nullptr, Thi);
        conv_mfma<1><<<512, blk, 0, stream>>>(
            Thi, convw_hi + l2 * 9216, convw_lo + l2 * 9216,
            bn2g + i * 32, bn2b + i * 32, bn2m + i * 32, bn2v + i * 32,
            c2b + i * 32, Xhi, Xhi);
    }

    // --- GEMM weight conversion (SRU batched via z) ---
    wconv_t<<<dim3(32, 16, 1), blk, 0, stream>>>(projW, proj_bt, 2048, 1024, 0, 0, 0);
    wconv_t<<<dim3(16, 32, 8), blk, 0, stream>>>(sruW, sru_bt, 1024, 2048, 1,
                                                 2097152, 2097152);
    wconv_t<<<dim3(16, 8, 1), blk, 0, stream>>>(W1, w1t, 1024, 512, 0, 0, 0);

    // --- gather to bf16 rows ---
    gather_pad<<<dim3(32, 16), blk, 0, stream>>>(Xhi, xrow_bf);

    // --- proj GEMM: (8192,2048)@(2048,1024) -> cbuf fp32 ---
    gemm_bf16<0><<<dim3(8, 64), blk, 0, stream>>>(
        xrow_bf, proj_bt, cbuf, 8192, 1024, 2048);

    // --- SRU layers: LN/lnh -> gemm256(split U) -> chain scan ---
    for (int l = 0; l < 4; ++l) {
        if (l == 0)
            layernorm1024_bf<<<8192, blk, 0, stream>>>(
                cbuf, sruLNg, sruLNb, xn_bf);
        else
            lnh<<<8192, blk, 0, stream>>>(
                cbuf, Uout, sruV + (l - 1) * 2048, sruB + (l - 1) * 2048,
                sruLNg + l * 1024, sruLNb + l * 1024, xn_bf);
        gemm256_bf16<<<dim3(16, 32), dim3(512), 0, stream>>>(
            xn_bf, sru_bt + (size_t)l * 4194304, Uchain, Uout, 8192, 4096, 1024);
        scan_c<<<256, dim3(64), 0, stream>>>(
            (const uint*)Uchain, sruV + l * 2048, sruB + l * 2048, cbuf);
    }

    // --- classifier (h of layer 3 + cls LN fused) ---
    lnh<<<8192, blk, 0, stream>>>(
        cbuf, Uout, sruV + 3 * 2048, sruB + 3 * 2048, clsLNg, clsLNb, xn_bf);
    gemm_bf16<1><<<dim3(4, 64), blk, 0, stream>>>(
        xn_bf, w1t, h1, 8192, 512, 1024);
    cls_out<<<1024, blk, 0, stream>>>(h1, W2, out);
}